// Round 1
// 420.833 us; speedup vs baseline: 1.0585x; 1.0585x over previous
//
#include <hip/hip_runtime.h>
#include <cstdint>
#include <cstddef>

typedef unsigned short u16;
typedef float f32x4 __attribute__((ext_vector_type(4)));
typedef short short8 __attribute__((ext_vector_type(8)));
typedef int i32x4 __attribute__((ext_vector_type(4)));

// ---------------- helpers ----------------

__device__ __forceinline__ float geluf(float v) {  // exact (libm erff)
  return 0.5f * v * (1.0f + erff(v * 0.70710678118654752440f));
}

// Abramowitz-Stegun 7.1.26: |err| <= 1.5e-7 abs.
__device__ __forceinline__ float erf_fast(float x) {
  const float ax = fabsf(x);
  const float t = __builtin_amdgcn_rcpf(fmaf(0.3275911f, ax, 1.0f));
  float p = fmaf(1.061405429f, t, -1.453152027f);
  p = fmaf(p, t, 1.421413741f);
  p = fmaf(p, t, -0.284496736f);
  p = fmaf(p, t, 0.254829592f);
  p = p * t;
  const float e = __expf(-ax * ax);
  const float r = fmaf(-p, e, 1.0f);
  return copysignf(r, x);
}
__device__ __forceinline__ float gelu_fast(float v) {
  return 0.5f * v * (1.0f + erf_fast(v * 0.70710678118654752440f));
}

__device__ __forceinline__ u16 f2bf(float f) {  // RNE fp32 -> bf16 bits
  unsigned u = __float_as_uint(f);
  u = (u + 0x7FFFu + ((u >> 16) & 1u)) >> 16;
  return (u16)u;
}
__device__ __forceinline__ float bf2f(u16 h) {
  return __uint_as_float(((unsigned)h) << 16);
}

__device__ __forceinline__ void waveRed2(float& s, float& s2) {
#pragma unroll
  for (int m = 1; m < 64; m <<= 1) {
    s += __shfl_xor(s, m);
    s2 += __shfl_xor(s2, m);
  }
}

// ---------------- fused prep: nvphi + converts + router-LN ----------------
__global__ __launch_bounds__(256) void k_prep(
    const float* __restrict__ nv, const float* __restrict__ pW1,
    const float* __restrict__ pb1, float* __restrict__ nvphi,
    const float* __restrict__ pW2, u16* __restrict__ pW2T,
    const float* __restrict__ rW1, u16* __restrict__ rW1T,
    const float* __restrict__ rW2, u16* __restrict__ rW2T,
    const float* __restrict__ Wr2, u16* __restrict__ Wr2b,
    const float* __restrict__ x, const float* __restrict__ rn_g,
    const float* __restrict__ rn_b, float* __restrict__ xln) {
  __shared__ float nvs[128];
  __shared__ float red[8];
  const int b = blockIdx.x, tid = threadIdx.x;
  if (b < 2048) {
    const int n = b;
    if (tid < 128) nvs[tid] = nv[n * 128 + tid];
    __syncthreads();
    float s = pb1[tid];
#pragma unroll 4
    for (int i = 0; i < 128; ++i) s = fmaf(nvs[i], pW1[i * 256 + tid], s);
    nvphi[n * 256 + tid] = s;
  } else if (b < 2304) {
    const int n = b - 2048;
    pW2T[n * 256 + tid] = f2bf(pW2[tid * 256 + n]);
  } else if (b < 2816) {
    const int n = b - 2304;
    if (tid < 256) rW1T[(size_t)n * 256 + tid] = f2bf(rW1[(size_t)tid * 512 + n]);
  } else if (b < 3328) {
    const int n = b - 2816;
    for (int k = tid; k < 512; k += 256)
      rW2T[(size_t)n * 512 + k] = f2bf(rW2[(size_t)k * 512 + n]);
  } else if (b < 7424) {
    const int i = (b - 3328) * 256 + tid;
    Wr2b[i] = f2bf(Wr2[i]);
  } else {
    const int t = b - 7424;
    const float v0 = x[(size_t)t * 512 + tid];
    const float v1 = x[(size_t)t * 512 + 256 + tid];
    float s = v0 + v1, s2 = v0 * v0 + v1 * v1;
    waveRed2(s, s2);
    if ((tid & 63) == 0) { red[(tid >> 6) * 2] = s; red[(tid >> 6) * 2 + 1] = s2; }
    __syncthreads();
    s = red[0] + red[2] + red[4] + red[6];
    s2 = red[1] + red[3] + red[5] + red[7];
    const float mu = s * (1.f / 512.f);
    const float var = fmaxf(s2 * (1.f / 512.f) - mu * mu, 0.f);
    const float rstd = 1.f / sqrtf(var + 1e-5f);
    xln[(size_t)t * 512 + tid] = (v0 - mu) * rstd * rn_g[tid] + rn_b[tid];
    xln[(size_t)t * 512 + 256 + tid] =
        (v1 - mu) * rstd * rn_g[tid + 256] + rn_b[tid + 256];
  }
}

// ---------------- 128x128 fp32 GEMM, C = act(A[M,K] @ B[N,K]^T) ----------------
template <int GMODE, bool BF16OUT>
__global__ __launch_bounds__(256) void gemm8f(const float* __restrict__ A,
                                              const float* __restrict__ B,
                                              float* __restrict__ C,
                                              u16* __restrict__ Cb, int M,
                                              int N, int K) {
  __shared__ float As[16][132];
  __shared__ float Bs[16][132];
  const int tid = threadIdx.x;
  const int tm = tid >> 4, tn = tid & 15;
  const int m0 = blockIdx.y * 128, n0 = blockIdx.x * 128;
  const int sr = tid >> 1, sk = (tid & 1) * 8;
  const float* gA = &A[(size_t)(m0 + sr) * K + sk];
  const float* gB = &B[(size_t)(n0 + sr) * K + sk];
  float acc[8][8] = {};
  for (int k0 = 0; k0 < K; k0 += 16) {
    const float4 a0 = *(const float4*)&gA[k0];
    const float4 a1 = *(const float4*)&gA[k0 + 4];
    const float4 b0 = *(const float4*)&gB[k0];
    const float4 b1 = *(const float4*)&gB[k0 + 4];
    __syncthreads();
    As[sk + 0][sr] = a0.x; As[sk + 1][sr] = a0.y; As[sk + 2][sr] = a0.z; As[sk + 3][sr] = a0.w;
    As[sk + 4][sr] = a1.x; As[sk + 5][sr] = a1.y; As[sk + 6][sr] = a1.z; As[sk + 7][sr] = a1.w;
    Bs[sk + 0][sr] = b0.x; Bs[sk + 1][sr] = b0.y; Bs[sk + 2][sr] = b0.z; Bs[sk + 3][sr] = b0.w;
    Bs[sk + 4][sr] = b1.x; Bs[sk + 5][sr] = b1.y; Bs[sk + 6][sr] = b1.z; Bs[sk + 7][sr] = b1.w;
    __syncthreads();
#pragma unroll
    for (int k = 0; k < 16; ++k) {
      float a[8], b[8];
      *(float4*)&a[0] = *(const float4*)&As[k][tm * 8];
      *(float4*)&a[4] = *(const float4*)&As[k][tm * 8 + 4];
      *(float4*)&b[0] = *(const float4*)&Bs[k][tn * 8];
      *(float4*)&b[4] = *(const float4*)&Bs[k][tn * 8 + 4];
#pragma unroll
      for (int i = 0; i < 8; ++i)
#pragma unroll
        for (int j = 0; j < 8; ++j) acc[i][j] = fmaf(a[i], b[j], acc[i][j]);
    }
  }
#pragma unroll
  for (int i = 0; i < 8; ++i) {
    float4 o0, o1;
    float* p0 = (float*)&o0;
    float* p1 = (float*)&o1;
#pragma unroll
    for (int j = 0; j < 4; ++j) {
      float xv = acc[i][j], yv = acc[i][j + 4];
      if (GMODE == 1) { xv = gelu_fast(xv); yv = gelu_fast(yv); }
      if (GMODE == 2) { xv = geluf(xv); yv = geluf(yv); }
      p0[j] = xv; p1[j] = yv;
    }
    const size_t off = (size_t)(m0 + tm * 8 + i) * N + n0 + tn * 8;
    *(float4*)&C[off] = o0;
    *(float4*)&C[off + 4] = o1;
    if (BF16OUT) {
      ushort4 u0, u1;
      u0.x = f2bf(p0[0]); u0.y = f2bf(p0[1]); u0.z = f2bf(p0[2]); u0.w = f2bf(p0[3]);
      u1.x = f2bf(p1[0]); u1.y = f2bf(p1[1]); u1.z = f2bf(p1[2]); u1.w = f2bf(p1[3]);
      *(ushort4*)&Cb[off] = u0;
      *(ushort4*)&Cb[off + 4] = u1;
    }
  }
}

// ---------------- MFMA GEMM: C = act(A[M,K] @ B[N,K]^T + bias) ----------------
template <int GMODE, bool BIAS, int OUT>
__global__ __launch_bounds__(256) void gemm_mf(const u16* __restrict__ Ahi,
                                               const u16* __restrict__ Bhi,
                                               const float* __restrict__ bias,
                                               void* __restrict__ Cp, int M,
                                               int N, int K) {
  constexpr int ASZ = 64 * 40;
  constexpr int BSZ = 128 * 40;
  __shared__ __align__(16) u16 smem[ASZ + BSZ];
  u16* sAh = smem;
  u16* sBh = smem + ASZ;

  const int tid = threadIdx.x;
  const int w = tid >> 6, lane = tid & 63;
  const int q = lane >> 4, c = lane & 15;
  const int m0 = blockIdx.y * 64, n0 = blockIdx.x * 128;
  const int ra = tid >> 2, ka = (tid & 3) * 8;
  const int rb = tid >> 1, kb = (tid & 1) * 16;
  const u16* gAh = Ahi + (size_t)(m0 + ra) * K + ka;
  const u16* gBh = Bhi + (size_t)(n0 + rb) * K + kb;

  f32x4 acc[8];
#pragma unroll
  for (int ct = 0; ct < 8; ++ct) {
    const float bv = BIAS ? bias[n0 + ct * 16 + c] : 0.f;
    acc[ct] = (f32x4){bv, bv, bv, bv};
  }

  for (int k0 = 0; k0 < K; k0 += 32) {
    const i32x4 vah = *(const i32x4*)(gAh + k0);
    const i32x4 vbh0 = *(const i32x4*)(gBh + k0);
    const i32x4 vbh1 = *(const i32x4*)(gBh + k0 + 8);
    __syncthreads();
    *(i32x4*)&sAh[ra * 40 + ka] = vah;
    *(i32x4*)&sBh[rb * 40 + kb] = vbh0;
    *(i32x4*)&sBh[rb * 40 + kb + 8] = vbh1;
    __syncthreads();
    const int abase = (w * 16 + c) * 40 + q * 8;
    const short8 ah = *(const short8*)&sAh[abase];
#pragma unroll
    for (int ct = 0; ct < 8; ++ct) {
      const int bbase = (ct * 16 + c) * 40 + q * 8;
      const short8 bh = *(const short8*)&sBh[bbase];
      acc[ct] = __builtin_amdgcn_mfma_f32_16x16x32_bf16(ah, bh, acc[ct], 0, 0, 0);
    }
  }
#pragma unroll
  for (int ct = 0; ct < 8; ++ct) {
#pragma unroll
    for (int reg = 0; reg < 4; ++reg) {
      float v = acc[ct][reg];
      if (GMODE == 1) v = gelu_fast(v);
      const size_t off = (size_t)(m0 + w * 16 + q * 4 + reg) * N + n0 + ct * 16 + c;
      if (OUT == 0) ((float*)Cp)[off] = v;
      else          ((u16*)Cp)[off] = f2bf(v);
    }
  }
}

// ---------------- fused: top-64 (approx+exact rescore) THEN act ----------------
__global__ __launch_bounds__(256) void k_topk_act(
    const u16* __restrict__ scoresb, const float* __restrict__ h,
    const float* __restrict__ Wr2, const float* __restrict__ x,
    const float* __restrict__ W_in, int* __restrict__ idxout,
    float* __restrict__ act) {
  __shared__ float hs[512];
  __shared__ int redc[2][4];
  __shared__ int cand[160];
  __shared__ float cex[160];
  __shared__ int selidx[64];
  __shared__ unsigned ccnt;
  const int t = blockIdx.x, tid = threadIdx.x;
  hs[tid] = h[(size_t)t * 512 + tid];
  hs[tid + 256] = h[(size_t)t * 512 + 256 + tid];
  unsigned key[8];
#pragma unroll
  for (int j = 0; j < 8; ++j) {
    const unsigned u = (unsigned)scoresb[(size_t)t * 2048 + tid + 256 * j];
    key[j] = (u & 0x8000u) ? (0xFFFFu & ~u) : (u | 0x8000u);
  }
  if (tid == 0) ccnt = 0u;
  // approx radix select (16 bits, 1 barrier/iter via double buffer)
  unsigned lo = 0u, hi = 0xFFFFu;
  int pb = 0;
  while (lo < hi) {
    const unsigned mid = (lo + hi + 1u) >> 1;
    int c = 0;
#pragma unroll
    for (int j = 0; j < 8; ++j) c += (key[j] >= mid);
#pragma unroll
    for (int m = 1; m < 64; m <<= 1) c += __shfl_xor(c, m);
    if ((tid & 63) == 0) redc[pb][tid >> 6] = c;
    __syncthreads();
    const int total = redc[pb][0] + redc[pb][1] + redc[pb][2] + redc[pb][3];
    if (total >= 96) lo = mid; else hi = mid - 1;
    pb ^= 1;
  }
#pragma unroll
  for (int j = 0; j < 8; ++j) {
    if (key[j] >= lo) {
      const unsigned pos = atomicAdd(&ccnt, 1u);
      if (pos < 160u) cand[pos] = tid + 256 * j;
    }
  }
  __syncthreads();
  const int cnt = (int)(ccnt < 160u ? ccnt : 160u);
  // exact fp32 rescore of candidates (lane-consecutive, coalesced)
  const int wv = tid >> 6, l = tid & 63;
  for (int ci = wv; ci < cnt; ci += 4) {
    const float* Wr = Wr2 + (size_t)cand[ci] * 512;
    float s = 0.f;
#pragma unroll
    for (int j = 0; j < 8; ++j) s = fmaf(Wr[l + 64 * j], hs[l + 64 * j], s);
#pragma unroll
    for (int m = 1; m < 64; m <<= 1) s += __shfl_xor(s, m);
    if (l == 0) cex[ci] = s;
  }
  __syncthreads();
  // rank-based exact top-64 (no barriers in loop; LDS broadcast reads)
  if (tid < cnt) {
    const float my = cex[tid];
    const int myi = cand[tid];
    int rank = 0;
    for (int j = 0; j < cnt; ++j) {
      const float oj = cex[j];
      const int oi = cand[j];
      rank += (oj > my) || (oj == my && oi < myi);
    }
    if (rank < 64) {
      selidx[rank] = myi;
      idxout[(size_t)t * 64 + rank] = myi;
    }
  }
  __syncthreads();
  // ---- Part 2: act (reuse hs for x) ----
  hs[tid] = x[(size_t)t * 512 + tid];
  hs[tid + 256] = x[(size_t)t * 512 + 256 + tid];
  __syncthreads();
  const float4 xa = *(const float4*)&hs[l * 8];
  const float4 xb = *(const float4*)&hs[l * 8 + 4];
  for (int qq = 0; qq < 16; ++qq) {
    const int k = wv * 16 + qq;
    const int n = selidx[k];
    const float* Wr = W_in + (size_t)n * 512 + l * 8;
    const float4 wa = *(const float4*)Wr;
    const float4 wb = *(const float4*)(Wr + 4);
    float s = wa.x * xa.x;
    s = fmaf(wa.y, xa.y, s); s = fmaf(wa.z, xa.z, s); s = fmaf(wa.w, xa.w, s);
    s = fmaf(wb.x, xb.x, s); s = fmaf(wb.y, xb.y, s);
    s = fmaf(wb.z, xb.z, s); s = fmaf(wb.w, xb.w, s);
#pragma unroll
    for (int m = 1; m < 64; m <<= 1) s += __shfl_xor(s, m);
    if (l == 0) act[(size_t)t * 64 + k] = gelu_fast(s);
  }
}

// ---------------- fused phi + rho-LN (one token per block) ----------------
// R14: column-split Phase B. Each wave owns all 64 rows x 64 output cols;
// B-fragments come straight from L2 (pW2T is 128KB, L2-resident; each wave
// reads a disjoint 32KB slice as dense 64B lines) -> no Bs LDS, no staging,
// ZERO barriers in the MFMA loop (was 16). Phase C per-lane state shrinks
// 16->4 cols (saves ~36 VGPR); LN2 row-sums now cross-wave via small LDS
// reduce. LDS 51.7->34.4KB; launch_bounds(256,3) targets 3 blocks/CU.
__global__ __launch_bounds__(256, 3) void k_phi(
    const float* __restrict__ nvphi, const float* __restrict__ pW1,
    const float* __restrict__ pln1_g, const float* __restrict__ pln1_b,
    const u16* __restrict__ pW2T, const float* __restrict__ pb2,
    const float* __restrict__ pln2_g, const float* __restrict__ pln2_b,
    const int* __restrict__ idx, const float* __restrict__ act,
    const float* __restrict__ rln_g, const float* __restrict__ rln_b,
    u16* __restrict__ rh) {
  __shared__ __align__(16) u16 h1s[64 * 264];  // 33792 B; Phase C aliases as float scratch
  __shared__ float red[8];
  __shared__ int idxs[64];
  __shared__ float acts[64];
  const int tid = threadIdx.x;
  const int t = blockIdx.x;
  const int w = tid >> 6, lane = tid & 63;
  const int q = lane >> 4, c = lane & 15;
  if (tid < 64) {
    idxs[tid] = idx[(size_t)t * 64 + tid];
    acts[tid] = act[(size_t)t * 64 + tid];
  }
  __syncthreads();  // B1
  // ---- Phase A: h1 = bf16(gelu(LN1(nvphi[n] + act*pW1[128,:]))) ----
  {
    f32x4 w4[4], g1[4], b1[4];
#pragma unroll
    for (int j = 0; j < 4; ++j) {
      w4[j] = *(const f32x4*)&pW1[128 * 256 + c * 16 + j * 4];
      g1[j] = *(const f32x4*)&pln1_g[c * 16 + j * 4];
      b1[j] = *(const f32x4*)&pln1_b[c * 16 + j * 4];
    }
#pragma unroll 2
    for (int rd = 0; rd < 4; ++rd) {
      const int p = w * 16 + rd * 4 + q;
      const int n = idxs[p];
      const float av = acts[p];
      f32x4 v[4];
      float s = 0.f, s2 = 0.f;
#pragma unroll
      for (int j = 0; j < 4; ++j) {
        const f32x4 nv = *(const f32x4*)&nvphi[(size_t)n * 256 + c * 16 + j * 4];
#pragma unroll
        for (int u = 0; u < 4; ++u) {
          v[j][u] = nv[u] + av * w4[j][u];
          s += v[j][u];
          s2 = fmaf(v[j][u], v[j][u], s2);
        }
      }
#pragma unroll
      for (int m = 1; m < 16; m <<= 1) { s += __shfl_xor(s, m); s2 += __shfl_xor(s2, m); }
      const float mu = s * (1.f / 256.f);
      const float var = fmaxf(s2 * (1.f / 256.f) - mu * mu, 0.f);
      const float rstd = 1.f / sqrtf(var + 1e-5f);
      short8 lo, hi;
#pragma unroll
      for (int j = 0; j < 4; ++j)
#pragma unroll
        for (int u = 0; u < 4; ++u) {
          const float hv = gelu_fast((v[j][u] - mu) * rstd * g1[j][u] + b1[j][u]);
          if (j < 2) lo[j * 4 + u] = (short)f2bf(hv);
          else       hi[(j - 2) * 4 + u] = (short)f2bf(hv);
        }
      *(short8*)&h1s[p * 264 + c * 16] = lo;
      *(short8*)&h1s[p * 264 + c * 16 + 8] = hi;
    }
  }
  __syncthreads();  // B2 (h1s is read cross-wave below)
  // ---- Phase B: acc[mt][nt] covers rows mt*16+q*4+reg, cols w*64+nt*16+c ----
  f32x4 acc[4][4];
#pragma unroll
  for (int nt = 0; nt < 4; ++nt) {
    const float bz = pb2[w * 64 + nt * 16 + c];
#pragma unroll
    for (int mt = 0; mt < 4; ++mt) acc[mt][nt] = (f32x4){bz, bz, bz, bz};
  }
  const u16* Bb = pW2T + ((size_t)(w * 64 + c) << 8) + q * 8;
#pragma unroll 2
  for (int ks = 0; ks < 8; ++ks) {
    short8 a[4], b[4];
#pragma unroll
    for (int mt = 0; mt < 4; ++mt)
      a[mt] = *(const short8*)&h1s[(mt * 16 + c) * 264 + ks * 32 + q * 8];
#pragma unroll
    for (int nt = 0; nt < 4; ++nt)
      b[nt] = *(const short8*)&Bb[nt * 4096 + ks * 32];
#pragma unroll
    for (int mt = 0; mt < 4; ++mt)
#pragma unroll
      for (int nt = 0; nt < 4; ++nt)
        acc[mt][nt] =
            __builtin_amdgcn_mfma_f32_16x16x32_bf16(a[mt], b[nt], acc[mt][nt], 0, 0, 0);
  }
  __syncthreads();  // B3 (all waves done reading h1s; safe to alias)
  // ---- Phase C: LN2 per row (256 cols span 4 waves) + k-sum ----
  // scratch layout in buf: pS[0..255] (w*64+r), pS2[256..511],
  // tS[512..575], tS2[576..639], agg[640..895]
  float* buf = (float*)h1s;
#pragma unroll
  for (int mt = 0; mt < 4; ++mt)
#pragma unroll
    for (int reg = 0; reg < 4; ++reg) {
      float s = acc[mt][0][reg] + acc[mt][1][reg] + acc[mt][2][reg] + acc[mt][3][reg];
      float s2 = acc[mt][0][reg] * acc[mt][0][reg];
      s2 = fmaf(acc[mt][1][reg], acc[mt][1][reg], s2);
      s2 = fmaf(acc[mt][2][reg], acc[mt][2][reg], s2);
      s2 = fmaf(acc[mt][3][reg], acc[mt][3][reg], s2);
#pragma unroll
      for (int m = 1; m < 16; m <<= 1) { s += __shfl_xor(s, m); s2 += __shfl_xor(s2, m); }
      if (c == 0) {
        const int r = mt * 16 + q * 4 + reg;
        buf[w * 64 + r] = s;
        buf[256 + w * 64 + r] = s2;
      }
    }
  __syncthreads();  // B4
  if (tid < 128) {
    const int r = tid & 63, which = tid >> 6;
    const float tot = buf[which * 256 + r] + buf[which * 256 + 64 + r] +
                      buf[which * 256 + 128 + r] + buf[which * 256 + 192 + r];
    buf[512 + which * 64 + r] = tot;
  }
  __syncthreads();  // B5
  float g2v[4], b2v[4], aggl[4];
#pragma unroll
  for (int nt = 0; nt < 4; ++nt) {
    g2v[nt] = pln2_g[w * 64 + nt * 16 + c];
    b2v[nt] = pln2_b[w * 64 + nt * 16 + c];
    aggl[nt] = 0.f;
  }
#pragma unroll
  for (int mt = 0; mt < 4; ++mt)
#pragma unroll
    for (int reg = 0; reg < 4; ++reg) {
      const int r = mt * 16 + q * 4 + reg;
      const float s = buf[512 + r], s2 = buf[576 + r];
      const float mu = s * (1.f / 256.f);
      const float var = fmaxf(s2 * (1.f / 256.f) - mu * mu, 0.f);
      const float rstd = 1.f / sqrtf(var + 1e-5f);
#pragma unroll
      for (int nt = 0; nt < 4; ++nt)
        aggl[nt] = fmaf((acc[mt][nt][reg] - mu) * rstd, g2v[nt], aggl[nt] + b2v[nt]);
    }
  // sum over the q-partitioned rows -> full 64-row aggregate per column
#pragma unroll
  for (int nt = 0; nt < 4; ++nt) {
    float vs = aggl[nt];
    vs += __shfl_xor(vs, 16);
    vs += __shfl_xor(vs, 32);
    if (q == 0) buf[640 + w * 64 + nt * 16 + c] = vs;
  }
  __syncthreads();  // B6
  // ---- fused rho-LN over 256 ----
  const float v = buf[640 + tid];
  float s = v, s2 = v * v;
  waveRed2(s, s2);
  if ((tid & 63) == 0) { red[(tid >> 6) * 2] = s; red[(tid >> 6) * 2 + 1] = s2; }
  __syncthreads();  // B7
  s = red[0] + red[2] + red[4] + red[6];
  s2 = red[1] + red[3] + red[5] + red[7];
  const float mu = s * (1.f / 256.f);
  const float var = fmaxf(s2 * (1.f / 256.f) - mu * mu, 0.f);
  const float rstd = 1.f / sqrtf(var + 1e-5f);
  rh[(size_t)t * 256 + tid] = f2bf((v - mu) * rstd * rln_g[tid] + rln_b[tid]);
}

// ---------------- launch ----------------
extern "C" void kernel_launch(void* const* d_in, const int* in_sizes, int n_in,
                              void* d_out, int out_size, void* d_ws, size_t ws_size,
                              hipStream_t stream) {
  const float* x = (const float*)d_in[0];
  const float* W_in = (const float*)d_in[1];
  const float* nv = (const float*)d_in[2];
  const float* Wr1 = (const float*)d_in[3];
  const float* Wr2 = (const float*)d_in[4];
  const float* rn_g = (const float*)d_in[5];
  const float* rn_b = (const float*)d_in[6];
  const float* pW1 = (const float*)d_in[7];
  const float* pb1 = (const float*)d_in[8];
  const float* pln1_g = (const float*)d_in[9];
  const float* pln1_b = (const float*)d_in[10];
  const float* pW2 = (const float*)d_in[11];
  const float* pb2 = (const float*)d_in[12];
  const float* pln2_g = (const float*)d_in[13];
  const float* pln2_b = (const float*)d_in[14];
  const float* rln_g = (const float*)d_in[15];
  const float* rln_b = (const float*)d_in[16];
  const float* rW1 = (const float*)d_in[17];
  const float* rb1 = (const float*)d_in[18];
  const float* rW2 = (const float*)d_in[19];
  const float* rb2 = (const float*)d_in[20];
  float* out = (float*)d_out;
  const int T = in_sizes[0] / 512;  // 4096

  float* ws = (float*)d_ws;
  float* xln = ws;    ws += (size_t)T * 512;
  float* h = ws;      ws += (size_t)T * 512;
  float* nvphi = ws;  ws += (size_t)2048 * 256;
  float* actb = ws;   ws += (size_t)T * 64;
  int* idx = (int*)ws;   ws += (size_t)T * 64;
  u16* scoresb = (u16*)ws; ws += (size_t)T * 2048 / 2;
  u16* hb = (u16*)ws;    ws += (size_t)T * 512 / 2;
  u16* Wr2b = (u16*)ws;  ws += (size_t)2048 * 512 / 2;
  u16* pW2T = (u16*)ws;  ws += (size_t)2048 * 256 / 2;
  u16* rh = (u16*)ws;    ws += (size_t)T * 256 / 2;
  u16* t1b = (u16*)ws;   ws += (size_t)T * 512 / 2;
  u16* rW1T = (u16*)ws;  ws += (size_t)512 * 256 / 2;
  u16* rW2T = (u16*)ws;  ws += (size_t)512 * 512 / 2;

  k_prep<<<7424 + T, 256, 0, stream>>>(nv, pW1, pb1, nvphi, pW2, pW2T, rW1,
                                       rW1T, rW2, rW2T, Wr2, Wr2b, x, rn_g,
                                       rn_b, xln);
  gemm8f<2, true><<<dim3(512 / 128, T / 128), 256, 0, stream>>>(
      xln, Wr1, h, hb, T, 512, 512);
  gemm_mf<0, false, 1><<<dim3(2048 / 128, T / 64), 256, 0, stream>>>(
      hb, Wr2b, nullptr, scoresb, T, 2048, 512);
  k_topk_act<<<T, 256, 0, stream>>>(scoresb, h, Wr2, x, W_in, idx, actb);
  k_phi<<<T, 256, 0, stream>>>(nvphi, pW1, pln1_g, pln1_b, pW2T, pb2, pln2_g,
                               pln2_b, idx, actb, rln_g, rln_b, rh);
  gemm_mf<1, true, 1><<<dim3(512 / 128, T / 64), 256, 0, stream>>>(
      rh, rW1T, rb1, t1b, T, 512, 256);
  gemm_mf<0, true, 0><<<dim3(512 / 128, T / 64), 256, 0, stream>>>(
      t1b, rW2T, rb2, out, T, 512, 512);
}

// Round 2
// 415.936 us; speedup vs baseline: 1.0710x; 1.0118x over previous
//
#include <hip/hip_runtime.h>
#include <cstdint>
#include <cstddef>

typedef unsigned short u16;
typedef float f32x4 __attribute__((ext_vector_type(4)));
typedef float f32x2 __attribute__((ext_vector_type(2)));
typedef short short8 __attribute__((ext_vector_type(8)));
typedef int i32x4 __attribute__((ext_vector_type(4)));

// ---------------- helpers ----------------

__device__ __forceinline__ float geluf(float v) {  // exact (libm erff)
  return 0.5f * v * (1.0f + erff(v * 0.70710678118654752440f));
}

// Abramowitz-Stegun 7.1.26: |err| <= 1.5e-7 abs.
__device__ __forceinline__ float erf_fast(float x) {
  const float ax = fabsf(x);
  const float t = __builtin_amdgcn_rcpf(fmaf(0.3275911f, ax, 1.0f));
  float p = fmaf(1.061405429f, t, -1.453152027f);
  p = fmaf(p, t, 1.421413741f);
  p = fmaf(p, t, -0.284496736f);
  p = fmaf(p, t, 0.254829592f);
  p = p * t;
  const float e = __expf(-ax * ax);
  const float r = fmaf(-p, e, 1.0f);
  return copysignf(r, x);
}
__device__ __forceinline__ float gelu_fast(float v) {
  return 0.5f * v * (1.0f + erf_fast(v * 0.70710678118654752440f));
}

__device__ __forceinline__ u16 f2bf(float f) {  // RNE fp32 -> bf16 bits
  unsigned u = __float_as_uint(f);
  u = (u + 0x7FFFu + ((u >> 16) & 1u)) >> 16;
  return (u16)u;
}
__device__ __forceinline__ float bf2f(u16 h) {
  return __uint_as_float(((unsigned)h) << 16);
}

// packed RNE f32x2 -> bf16x2 (single instruction; same rounding as f2bf on
// finite values)
__device__ __forceinline__ unsigned cvt_pk_bf16(float lo, float hi) {
  unsigned r;
  asm("v_cvt_pk_bf16_f32 %0, %1, %2" : "=v"(r) : "v"(lo), "v"(hi));
  return r;
}

__device__ __forceinline__ void waveRed2(float& s, float& s2) {
#pragma unroll
  for (int m = 1; m < 64; m <<= 1) {
    s += __shfl_xor(s, m);
    s2 += __shfl_xor(s2, m);
  }
}

// ---------------- fused prep: nvphi(+stats) + converts + router-LN ----------------
__global__ __launch_bounds__(256) void k_prep(
    const float* __restrict__ nv, const float* __restrict__ pW1,
    const float* __restrict__ pb1, float* __restrict__ nvphi,
    float* __restrict__ nvstats, const float* __restrict__ pW2,
    u16* __restrict__ pW2T, const float* __restrict__ rW1,
    u16* __restrict__ rW1T, const float* __restrict__ rW2,
    u16* __restrict__ rW2T, const float* __restrict__ Wr2,
    u16* __restrict__ Wr2b, const float* __restrict__ x,
    const float* __restrict__ rn_g, const float* __restrict__ rn_b,
    float* __restrict__ xln) {
  __shared__ float nvs[128];
  __shared__ float red[12];
  const int b = blockIdx.x, tid = threadIdx.x;
  if (b < 2048) {
    const int n = b;
    if (tid < 128) nvs[tid] = nv[n * 128 + tid];
    __syncthreads();
    float s = pb1[tid];
#pragma unroll 4
    for (int i = 0; i < 128; ++i) s = fmaf(nvs[i], pW1[i * 256 + tid], s);
    nvphi[n * 256 + tid] = s;
    // row stats for analytic LN1 in k_phi: mean(nv), mean(nv^2), mean(nv*w)
    const float wv_ = pW1[128 * 256 + tid];
    float a1 = s, a2 = s * s, a3 = s * wv_;
#pragma unroll
    for (int m = 1; m < 64; m <<= 1) {
      a1 += __shfl_xor(a1, m);
      a2 += __shfl_xor(a2, m);
      a3 += __shfl_xor(a3, m);
    }
    if ((tid & 63) == 0) {
      red[(tid >> 6) * 3 + 0] = a1;
      red[(tid >> 6) * 3 + 1] = a2;
      red[(tid >> 6) * 3 + 2] = a3;
    }
    __syncthreads();
    if (tid < 3) {
      const float v = red[tid] + red[3 + tid] + red[6 + tid] + red[9 + tid];
      nvstats[n * 4 + tid] = v * (1.f / 256.f);
    } else if (tid == 3) {
      nvstats[n * 4 + 3] = 0.f;
    }
  } else if (b < 2304) {
    const int n = b - 2048;
    pW2T[n * 256 + tid] = f2bf(pW2[tid * 256 + n]);
  } else if (b < 2816) {
    const int n = b - 2304;
    if (tid < 256) rW1T[(size_t)n * 256 + tid] = f2bf(rW1[(size_t)tid * 512 + n]);
  } else if (b < 3328) {
    const int n = b - 2816;
    for (int k = tid; k < 512; k += 256)
      rW2T[(size_t)n * 512 + k] = f2bf(rW2[(size_t)k * 512 + n]);
  } else if (b < 7424) {
    const int i = (b - 3328) * 256 + tid;
    Wr2b[i] = f2bf(Wr2[i]);
  } else {
    const int t = b - 7424;
    const float v0 = x[(size_t)t * 512 + tid];
    const float v1 = x[(size_t)t * 512 + 256 + tid];
    float s = v0 + v1, s2 = v0 * v0 + v1 * v1;
    waveRed2(s, s2);
    if ((tid & 63) == 0) { red[(tid >> 6) * 2] = s; red[(tid >> 6) * 2 + 1] = s2; }
    __syncthreads();
    s = red[0] + red[2] + red[4] + red[6];
    s2 = red[1] + red[3] + red[5] + red[7];
    const float mu = s * (1.f / 512.f);
    const float var = fmaxf(s2 * (1.f / 512.f) - mu * mu, 0.f);
    const float rstd = 1.f / sqrtf(var + 1e-5f);
    xln[(size_t)t * 512 + tid] = (v0 - mu) * rstd * rn_g[tid] + rn_b[tid];
    xln[(size_t)t * 512 + 256 + tid] =
        (v1 - mu) * rstd * rn_g[tid + 256] + rn_b[tid + 256];
  }
}

// ---------------- 128x128 fp32 GEMM, C = act(A[M,K] @ B[N,K]^T) ----------------
template <int GMODE, bool BF16OUT>
__global__ __launch_bounds__(256) void gemm8f(const float* __restrict__ A,
                                              const float* __restrict__ B,
                                              float* __restrict__ C,
                                              u16* __restrict__ Cb, int M,
                                              int N, int K) {
  __shared__ float As[16][132];
  __shared__ float Bs[16][132];
  const int tid = threadIdx.x;
  const int tm = tid >> 4, tn = tid & 15;
  const int m0 = blockIdx.y * 128, n0 = blockIdx.x * 128;
  const int sr = tid >> 1, sk = (tid & 1) * 8;
  const float* gA = &A[(size_t)(m0 + sr) * K + sk];
  const float* gB = &B[(size_t)(n0 + sr) * K + sk];
  float acc[8][8] = {};
  for (int k0 = 0; k0 < K; k0 += 16) {
    const float4 a0 = *(const float4*)&gA[k0];
    const float4 a1 = *(const float4*)&gA[k0 + 4];
    const float4 b0 = *(const float4*)&gB[k0];
    const float4 b1 = *(const float4*)&gB[k0 + 4];
    __syncthreads();
    As[sk + 0][sr] = a0.x; As[sk + 1][sr] = a0.y; As[sk + 2][sr] = a0.z; As[sk + 3][sr] = a0.w;
    As[sk + 4][sr] = a1.x; As[sk + 5][sr] = a1.y; As[sk + 6][sr] = a1.z; As[sk + 7][sr] = a1.w;
    Bs[sk + 0][sr] = b0.x; Bs[sk + 1][sr] = b0.y; Bs[sk + 2][sr] = b0.z; Bs[sk + 3][sr] = b0.w;
    Bs[sk + 4][sr] = b1.x; Bs[sk + 5][sr] = b1.y; Bs[sk + 6][sr] = b1.z; Bs[sk + 7][sr] = b1.w;
    __syncthreads();
#pragma unroll
    for (int k = 0; k < 16; ++k) {
      float a[8], b[8];
      *(float4*)&a[0] = *(const float4*)&As[k][tm * 8];
      *(float4*)&a[4] = *(const float4*)&As[k][tm * 8 + 4];
      *(float4*)&b[0] = *(const float4*)&Bs[k][tn * 8];
      *(float4*)&b[4] = *(const float4*)&Bs[k][tn * 8 + 4];
#pragma unroll
      for (int i = 0; i < 8; ++i)
#pragma unroll
        for (int j = 0; j < 8; ++j) acc[i][j] = fmaf(a[i], b[j], acc[i][j]);
    }
  }
#pragma unroll
  for (int i = 0; i < 8; ++i) {
    float4 o0, o1;
    float* p0 = (float*)&o0;
    float* p1 = (float*)&o1;
#pragma unroll
    for (int j = 0; j < 4; ++j) {
      float xv = acc[i][j], yv = acc[i][j + 4];
      if (GMODE == 1) { xv = gelu_fast(xv); yv = gelu_fast(yv); }
      if (GMODE == 2) { xv = geluf(xv); yv = geluf(yv); }
      p0[j] = xv; p1[j] = yv;
    }
    const size_t off = (size_t)(m0 + tm * 8 + i) * N + n0 + tn * 8;
    *(float4*)&C[off] = o0;
    *(float4*)&C[off + 4] = o1;
    if (BF16OUT) {
      ushort4 u0, u1;
      u0.x = f2bf(p0[0]); u0.y = f2bf(p0[1]); u0.z = f2bf(p0[2]); u0.w = f2bf(p0[3]);
      u1.x = f2bf(p1[0]); u1.y = f2bf(p1[1]); u1.z = f2bf(p1[2]); u1.w = f2bf(p1[3]);
      *(ushort4*)&Cb[off] = u0;
      *(ushort4*)&Cb[off + 4] = u1;
    }
  }
}

// ---------------- MFMA GEMM: C = act(A[M,K] @ B[N,K]^T + bias) ----------------
template <int GMODE, bool BIAS, int OUT>
__global__ __launch_bounds__(256) void gemm_mf(const u16* __restrict__ Ahi,
                                               const u16* __restrict__ Bhi,
                                               const float* __restrict__ bias,
                                               void* __restrict__ Cp, int M,
                                               int N, int K) {
  constexpr int ASZ = 64 * 40;
  constexpr int BSZ = 128 * 40;
  __shared__ __align__(16) u16 smem[ASZ + BSZ];
  u16* sAh = smem;
  u16* sBh = smem + ASZ;

  const int tid = threadIdx.x;
  const int w = tid >> 6, lane = tid & 63;
  const int q = lane >> 4, c = lane & 15;
  const int m0 = blockIdx.y * 64, n0 = blockIdx.x * 128;
  const int ra = tid >> 2, ka = (tid & 3) * 8;
  const int rb = tid >> 1, kb = (tid & 1) * 16;
  const u16* gAh = Ahi + (size_t)(m0 + ra) * K + ka;
  const u16* gBh = Bhi + (size_t)(n0 + rb) * K + kb;

  f32x4 acc[8];
#pragma unroll
  for (int ct = 0; ct < 8; ++ct) {
    const float bv = BIAS ? bias[n0 + ct * 16 + c] : 0.f;
    acc[ct] = (f32x4){bv, bv, bv, bv};
  }

  for (int k0 = 0; k0 < K; k0 += 32) {
    const i32x4 vah = *(const i32x4*)(gAh + k0);
    const i32x4 vbh0 = *(const i32x4*)(gBh + k0);
    const i32x4 vbh1 = *(const i32x4*)(gBh + k0 + 8);
    __syncthreads();
    *(i32x4*)&sAh[ra * 40 + ka] = vah;
    *(i32x4*)&sBh[rb * 40 + kb] = vbh0;
    *(i32x4*)&sBh[rb * 40 + kb + 8] = vbh1;
    __syncthreads();
    const int abase = (w * 16 + c) * 40 + q * 8;
    const short8 ah = *(const short8*)&sAh[abase];
#pragma unroll
    for (int ct = 0; ct < 8; ++ct) {
      const int bbase = (ct * 16 + c) * 40 + q * 8;
      const short8 bh = *(const short8*)&sBh[bbase];
      acc[ct] = __builtin_amdgcn_mfma_f32_16x16x32_bf16(ah, bh, acc[ct], 0, 0, 0);
    }
  }
#pragma unroll
  for (int ct = 0; ct < 8; ++ct) {
#pragma unroll
    for (int reg = 0; reg < 4; ++reg) {
      float v = acc[ct][reg];
      if (GMODE == 1) v = gelu_fast(v);
      const size_t off = (size_t)(m0 + w * 16 + q * 4 + reg) * N + n0 + ct * 16 + c;
      if (OUT == 0) ((float*)Cp)[off] = v;
      else          ((u16*)Cp)[off] = f2bf(v);
    }
  }
}

// ---------------- fused: top-64 (approx+exact rescore) THEN act ----------------
__global__ __launch_bounds__(256) void k_topk_act(
    const u16* __restrict__ scoresb, const float* __restrict__ h,
    const float* __restrict__ Wr2, const float* __restrict__ x,
    const float* __restrict__ W_in, int* __restrict__ idxout,
    float* __restrict__ act) {
  __shared__ float hs[512];
  __shared__ int redc[2][4];
  __shared__ int cand[160];
  __shared__ float cex[160];
  __shared__ int selidx[64];
  __shared__ unsigned ccnt;
  const int t = blockIdx.x, tid = threadIdx.x;
  hs[tid] = h[(size_t)t * 512 + tid];
  hs[tid + 256] = h[(size_t)t * 512 + 256 + tid];
  unsigned key[8];
#pragma unroll
  for (int j = 0; j < 8; ++j) {
    const unsigned u = (unsigned)scoresb[(size_t)t * 2048 + tid + 256 * j];
    key[j] = (u & 0x8000u) ? (0xFFFFu & ~u) : (u | 0x8000u);
  }
  if (tid == 0) ccnt = 0u;
  // approx radix select (16 bits, 1 barrier/iter via double buffer)
  unsigned lo = 0u, hi = 0xFFFFu;
  int pb = 0;
  while (lo < hi) {
    const unsigned mid = (lo + hi + 1u) >> 1;
    int c = 0;
#pragma unroll
    for (int j = 0; j < 8; ++j) c += (key[j] >= mid);
#pragma unroll
    for (int m = 1; m < 64; m <<= 1) c += __shfl_xor(c, m);
    if ((tid & 63) == 0) redc[pb][tid >> 6] = c;
    __syncthreads();
    const int total = redc[pb][0] + redc[pb][1] + redc[pb][2] + redc[pb][3];
    if (total >= 96) lo = mid; else hi = mid - 1;
    pb ^= 1;
  }
#pragma unroll
  for (int j = 0; j < 8; ++j) {
    if (key[j] >= lo) {
      const unsigned pos = atomicAdd(&ccnt, 1u);
      if (pos < 160u) cand[pos] = tid + 256 * j;
    }
  }
  __syncthreads();
  const int cnt = (int)(ccnt < 160u ? ccnt : 160u);
  // exact fp32 rescore of candidates (lane-consecutive, coalesced)
  const int wv = tid >> 6, l = tid & 63;
  for (int ci = wv; ci < cnt; ci += 4) {
    const float* Wr = Wr2 + (size_t)cand[ci] * 512;
    float s = 0.f;
#pragma unroll
    for (int j = 0; j < 8; ++j) s = fmaf(Wr[l + 64 * j], hs[l + 64 * j], s);
#pragma unroll
    for (int m = 1; m < 64; m <<= 1) s += __shfl_xor(s, m);
    if (l == 0) cex[ci] = s;
  }
  __syncthreads();
  // rank-based exact top-64 (no barriers in loop; LDS broadcast reads)
  if (tid < cnt) {
    const float my = cex[tid];
    const int myi = cand[tid];
    int rank = 0;
    for (int j = 0; j < cnt; ++j) {
      const float oj = cex[j];
      const int oi = cand[j];
      rank += (oj > my) || (oj == my && oi < myi);
    }
    if (rank < 64) {
      selidx[rank] = myi;
      idxout[(size_t)t * 64 + rank] = myi;
    }
  }
  __syncthreads();
  // ---- Part 2: act (reuse hs for x) ----
  hs[tid] = x[(size_t)t * 512 + tid];
  hs[tid + 256] = x[(size_t)t * 512 + 256 + tid];
  __syncthreads();
  const float4 xa = *(const float4*)&hs[l * 8];
  const float4 xb = *(const float4*)&hs[l * 8 + 4];
  for (int qq = 0; qq < 16; ++qq) {
    const int k = wv * 16 + qq;
    const int n = selidx[k];
    const float* Wr = W_in + (size_t)n * 512 + l * 8;
    const float4 wa = *(const float4*)Wr;
    const float4 wb = *(const float4*)(Wr + 4);
    float s = wa.x * xa.x;
    s = fmaf(wa.y, xa.y, s); s = fmaf(wa.z, xa.z, s); s = fmaf(wa.w, xa.w, s);
    s = fmaf(wb.x, xb.x, s); s = fmaf(wb.y, xb.y, s);
    s = fmaf(wb.z, xb.z, s); s = fmaf(wb.w, xb.w, s);
#pragma unroll
    for (int m = 1; m < 64; m <<= 1) s += __shfl_xor(s, m);
    if (l == 0) act[(size_t)t * 64 + k] = gelu_fast(s);
  }
}

// ---------------- fused phi + rho-LN (one token per block) ----------------
// R15: (a) analytic LN1 stats (nvstats precomputed in k_prep) kill all
// Phase-A shuffle reductions; (b) v_cvt_pk_bf16_f32 packs h1; (c) Phase-C
// LN2 stats via LDS-transpose reduce (stride-66, 2-way-max writes) instead
// of 128 ds_bpermute per thread. VGPR slack -> launch_bounds(256,4).
__global__ __launch_bounds__(256, 4) void k_phi(
    const float* __restrict__ nvphi, const float* __restrict__ nvstats,
    const float* __restrict__ pW1, const float* __restrict__ pln1_g,
    const float* __restrict__ pln1_b, const u16* __restrict__ pW2T,
    const float* __restrict__ pb2, const float* __restrict__ pln2_g,
    const float* __restrict__ pln2_b, const int* __restrict__ idx,
    const float* __restrict__ act, const float* __restrict__ rln_g,
    const float* __restrict__ rln_b, u16* __restrict__ rh) {
  __shared__ __align__(16) u16 h1s[64 * 264];  // 33792 B; Phase C aliases as float scratch
  __shared__ float rowstats[64 * 2];           // {mu, rstd} per h2 row
  __shared__ float red[8];
  __shared__ int idxs[64];
  __shared__ float acts[64];
  const int tid = threadIdx.x;
  const int t = blockIdx.x;
  const int w = tid >> 6, lane = tid & 63;
  const int q = lane >> 4, c = lane & 15;
  if (tid < 64) {
    idxs[tid] = idx[(size_t)t * 64 + tid];
    acts[tid] = act[(size_t)t * 64 + tid];
  }
  __syncthreads();  // B1
  // ---- Phase A: h1 = bf16(gelu(LN1(nvphi[n] + act*pW1[128,:]))) ----
  {
    f32x4 w4[4], g1[4], b1[4];
#pragma unroll
    for (int j = 0; j < 4; ++j) {
      w4[j] = *(const f32x4*)&pW1[128 * 256 + c * 16 + j * 4];
      g1[j] = *(const f32x4*)&pln1_g[c * 16 + j * 4];
      b1[j] = *(const f32x4*)&pln1_b[c * 16 + j * 4];
    }
    // global stats of the act-row w (same for all rows): mean, mean-square
    float sw = 0.f, sw2 = 0.f;
#pragma unroll
    for (int j = 0; j < 4; ++j)
#pragma unroll
      for (int u = 0; u < 4; ++u) {
        sw += w4[j][u];
        sw2 = fmaf(w4[j][u], w4[j][u], sw2);
      }
#pragma unroll
    for (int m = 1; m < 16; m <<= 1) {
      sw += __shfl_xor(sw, m);
      sw2 += __shfl_xor(sw2, m);
    }
    const float mw = sw * (1.f / 256.f), e2w = sw2 * (1.f / 256.f);
#pragma unroll 2
    for (int rd = 0; rd < 4; ++rd) {
      const int p = w * 16 + rd * 4 + q;
      const int n = idxs[p];
      const float a = acts[p];
      const f32x4 st = *(const f32x4*)&nvstats[n * 4];  // {mu_nv,E2_nv,Enw,0}
      const float mu = fmaf(a, mw, st.x);
      const float e2 = fmaf(a * a, e2w, fmaf(a + a, st.z, st.y));
      const float var = fmaxf(e2 - mu * mu, 0.f);
      const float rstd = 1.f / sqrtf(var + 1e-5f);
      const float nmr = -mu * rstd;
      unsigned pk[8];
#pragma unroll
      for (int j = 0; j < 4; ++j) {
        const f32x4 nv = *(const f32x4*)&nvphi[(size_t)n * 256 + c * 16 + j * 4];
        float hh[4];
#pragma unroll
        for (int u = 0; u < 4; ++u) {
          const float v = fmaf(a, w4[j][u], nv[u]);
          const float tt = fmaf(v, rstd, nmr);
          hh[u] = gelu_fast(fmaf(tt, g1[j][u], b1[j][u]));
        }
        pk[j * 2] = cvt_pk_bf16(hh[0], hh[1]);
        pk[j * 2 + 1] = cvt_pk_bf16(hh[2], hh[3]);
      }
      *(i32x4*)&h1s[p * 264 + c * 16] = (i32x4){(int)pk[0], (int)pk[1], (int)pk[2], (int)pk[3]};
      *(i32x4*)&h1s[p * 264 + c * 16 + 8] = (i32x4){(int)pk[4], (int)pk[5], (int)pk[6], (int)pk[7]};
    }
  }
  __syncthreads();  // B2 (h1s is read cross-wave below)
  // ---- Phase B: acc[mt][nt] covers rows mt*16+q*4+reg, cols w*64+nt*16+c ----
  f32x4 acc[4][4];
#pragma unroll
  for (int nt = 0; nt < 4; ++nt) {
    const float bz = pb2[w * 64 + nt * 16 + c];
#pragma unroll
    for (int mt = 0; mt < 4; ++mt) acc[mt][nt] = (f32x4){bz, bz, bz, bz};
  }
  const u16* Bb = pW2T + ((size_t)(w * 64 + c) << 8) + q * 8;
#pragma unroll 2
  for (int ks = 0; ks < 8; ++ks) {
    short8 a[4], b[4];
#pragma unroll
    for (int mt = 0; mt < 4; ++mt)
      a[mt] = *(const short8*)&h1s[(mt * 16 + c) * 264 + ks * 32 + q * 8];
#pragma unroll
    for (int nt = 0; nt < 4; ++nt)
      b[nt] = *(const short8*)&Bb[nt * 4096 + ks * 32];
#pragma unroll
    for (int mt = 0; mt < 4; ++mt)
#pragma unroll
      for (int nt = 0; nt < 4; ++nt)
        acc[mt][nt] =
            __builtin_amdgcn_mfma_f32_16x16x32_bf16(a[mt], b[nt], acc[mt][nt], 0, 0, 0);
  }
  __syncthreads();  // B3 (all waves done reading h1s; safe to alias)
  // ---- Phase C: LN2 stats via LDS transpose reduce ----
  // sbuf/s2buf: [64 rows][66] floats each (stride 66 -> 2-way-max write
  // conflicts, even 8/bank reads). 2*64*66*4 = 33792 B = h1s exactly.
  float* sbuf = (float*)h1s;
  float* s2buf = sbuf + 64 * 66;
#pragma unroll
  for (int mt = 0; mt < 4; ++mt)
#pragma unroll
    for (int reg = 0; reg < 4; ++reg) {
      const float v0 = acc[mt][0][reg], v1 = acc[mt][1][reg];
      const float v2 = acc[mt][2][reg], v3 = acc[mt][3][reg];
      const float s = (v0 + v1) + (v2 + v3);
      float s2 = v0 * v0;
      s2 = fmaf(v1, v1, s2);
      s2 = fmaf(v2, v2, s2);
      s2 = fmaf(v3, v3, s2);
      const int r = mt * 16 + q * 4 + reg;
      sbuf[r * 66 + w * 16 + c] = s;
      s2buf[r * 66 + w * 16 + c] = s2;
    }
  __syncthreads();  // B4
  {
    const int r = tid >> 2, seg = tid & 3;
    const float* rp = &sbuf[r * 66 + seg * 16];
    const float* rp2 = &s2buf[r * 66 + seg * 16];
    float ss = 0.f, ss2 = 0.f;
#pragma unroll
    for (int j = 0; j < 8; ++j) {
      const f32x2 u = *(const f32x2*)&rp[j * 2];
      const f32x2 u2 = *(const f32x2*)&rp2[j * 2];
      ss += u[0] + u[1];
      ss2 += u2[0] + u2[1];
    }
    ss += __shfl_xor(ss, 1);
    ss2 += __shfl_xor(ss2, 1);
    ss += __shfl_xor(ss, 2);
    ss2 += __shfl_xor(ss2, 2);
    if (seg == 0) {
      const float mu = ss * (1.f / 256.f);
      const float var = fmaxf(ss2 * (1.f / 256.f) - mu * mu, 0.f);
      const float rstd = 1.f / sqrtf(var + 1e-5f);
      rowstats[r * 2] = mu;
      rowstats[r * 2 + 1] = rstd;
    }
  }
  __syncthreads();  // B5
  // ---- LN2 apply + k-sum ----
  float g2v[4], b2v[4], aggl[4];
#pragma unroll
  for (int nt = 0; nt < 4; ++nt) {
    g2v[nt] = pln2_g[w * 64 + nt * 16 + c];
    b2v[nt] = pln2_b[w * 64 + nt * 16 + c];
    aggl[nt] = 16.f * b2v[nt];  // b2 added once per row, 16 rows per lane
  }
#pragma unroll
  for (int mt = 0; mt < 4; ++mt)
#pragma unroll
    for (int reg = 0; reg < 4; ++reg) {
      const int r = mt * 16 + q * 4 + reg;
      const f32x2 mr = *(const f32x2*)&rowstats[r * 2];
      const float nmr = -mr[0] * mr[1];
#pragma unroll
      for (int nt = 0; nt < 4; ++nt) {
        const float tt = fmaf(acc[mt][nt][reg], mr[1], nmr);
        aggl[nt] = fmaf(tt, g2v[nt], aggl[nt]);
      }
    }
  // sum over the q-partitioned rows -> full 64-row aggregate per column
  float* aggb = sbuf;  // words 0..255 dead after B5 reads
#pragma unroll
  for (int nt = 0; nt < 4; ++nt) {
    float vs = aggl[nt];
    vs += __shfl_xor(vs, 16);
    vs += __shfl_xor(vs, 32);
    if (q == 0) aggb[w * 64 + nt * 16 + c] = vs;
  }
  __syncthreads();  // B6
  // ---- fused rho-LN over 256 ----
  const float v = aggb[tid];
  float s = v, s2 = v * v;
  waveRed2(s, s2);
  if ((tid & 63) == 0) { red[(tid >> 6) * 2] = s; red[(tid >> 6) * 2 + 1] = s2; }
  __syncthreads();  // B7
  s = red[0] + red[2] + red[4] + red[6];
  s2 = red[1] + red[3] + red[5] + red[7];
  const float mu = s * (1.f / 256.f);
  const float var = fmaxf(s2 * (1.f / 256.f) - mu * mu, 0.f);
  const float rstd = 1.f / sqrtf(var + 1e-5f);
  rh[(size_t)t * 256 + tid] = f2bf((v - mu) * rstd * rln_g[tid] + rln_b[tid]);
}

// ---------------- launch ----------------
extern "C" void kernel_launch(void* const* d_in, const int* in_sizes, int n_in,
                              void* d_out, int out_size, void* d_ws, size_t ws_size,
                              hipStream_t stream) {
  const float* x = (const float*)d_in[0];
  const float* W_in = (const float*)d_in[1];
  const float* nv = (const float*)d_in[2];
  const float* Wr1 = (const float*)d_in[3];
  const float* Wr2 = (const float*)d_in[4];
  const float* rn_g = (const float*)d_in[5];
  const float* rn_b = (const float*)d_in[6];
  const float* pW1 = (const float*)d_in[7];
  const float* pb1 = (const float*)d_in[8];
  const float* pln1_g = (const float*)d_in[9];
  const float* pln1_b = (const float*)d_in[10];
  const float* pW2 = (const float*)d_in[11];
  const float* pb2 = (const float*)d_in[12];
  const float* pln2_g = (const float*)d_in[13];
  const float* pln2_b = (const float*)d_in[14];
  const float* rln_g = (const float*)d_in[15];
  const float* rln_b = (const float*)d_in[16];
  const float* rW1 = (const float*)d_in[17];
  const float* rb1 = (const float*)d_in[18];
  const float* rW2 = (const float*)d_in[19];
  const float* rb2 = (const float*)d_in[20];
  float* out = (float*)d_out;
  const int T = in_sizes[0] / 512;  // 4096

  float* ws = (float*)d_ws;
  float* xln = ws;    ws += (size_t)T * 512;
  float* h = ws;      ws += (size_t)T * 512;
  float* nvphi = ws;  ws += (size_t)2048 * 256;
  float* nvstats = ws; ws += (size_t)2048 * 4;
  float* actb = ws;   ws += (size_t)T * 64;
  int* idx = (int*)ws;   ws += (size_t)T * 64;
  u16* scoresb = (u16*)ws; ws += (size_t)T * 2048 / 2;
  u16* hb = (u16*)ws;    ws += (size_t)T * 512 / 2;
  u16* Wr2b = (u16*)ws;  ws += (size_t)2048 * 512 / 2;
  u16* pW2T = (u16*)ws;  ws += (size_t)2048 * 256 / 2;
  u16* rh = (u16*)ws;    ws += (size_t)T * 256 / 2;
  u16* t1b = (u16*)ws;   ws += (size_t)T * 512 / 2;
  u16* rW1T = (u16*)ws;  ws += (size_t)512 * 256 / 2;
  u16* rW2T = (u16*)ws;  ws += (size_t)512 * 512 / 2;

  k_prep<<<7424 + T, 256, 0, stream>>>(nv, pW1, pb1, nvphi, nvstats, pW2, pW2T,
                                       rW1, rW1T, rW2, rW2T, Wr2, Wr2b, x, rn_g,
                                       rn_b, xln);
  gemm8f<2, true><<<dim3(512 / 128, T / 128), 256, 0, stream>>>(
      xln, Wr1, h, hb, T, 512, 512);
  gemm_mf<0, false, 1><<<dim3(2048 / 128, T / 64), 256, 0, stream>>>(
      hb, Wr2b, nullptr, scoresb, T, 2048, 512);
  k_topk_act<<<T, 256, 0, stream>>>(scoresb, h, Wr2, x, W_in, idx, actb);
  k_phi<<<T, 256, 0, stream>>>(nvphi, nvstats, pW1, pln1_g, pln1_b, pW2T, pb2,
                               pln2_g, pln2_b, idx, actb, rln_g, rln_b, rh);
  gemm_mf<1, true, 1><<<dim3(512 / 128, T / 64), 256, 0, stream>>>(
      rh, rW1T, rb1, t1b, T, 512, 256);
  gemm_mf<0, true, 0><<<dim3(512 / 128, T / 64), 256, 0, stream>>>(
      t1b, rW2T, rb2, out, T, 512, 512);
}

// Round 3
// 409.648 us; speedup vs baseline: 1.0874x; 1.0153x over previous
//
#include <hip/hip_runtime.h>
#include <cstdint>
#include <cstddef>

typedef unsigned short u16;
typedef float f32x4 __attribute__((ext_vector_type(4)));
typedef float f32x2 __attribute__((ext_vector_type(2)));
typedef short short8 __attribute__((ext_vector_type(8)));
typedef int i32x4 __attribute__((ext_vector_type(4)));

// ---------------- helpers ----------------

__device__ __forceinline__ float geluf(float v) {  // exact (libm erff)
  return 0.5f * v * (1.0f + erff(v * 0.70710678118654752440f));
}

// Abramowitz-Stegun 7.1.26: |err| <= 1.5e-7 abs.
__device__ __forceinline__ float erf_fast(float x) {
  const float ax = fabsf(x);
  const float t = __builtin_amdgcn_rcpf(fmaf(0.3275911f, ax, 1.0f));
  float p = fmaf(1.061405429f, t, -1.453152027f);
  p = fmaf(p, t, 1.421413741f);
  p = fmaf(p, t, -0.284496736f);
  p = fmaf(p, t, 0.254829592f);
  p = p * t;
  const float e = __expf(-ax * ax);
  const float r = fmaf(-p, e, 1.0f);
  return copysignf(r, x);
}
__device__ __forceinline__ float gelu_fast(float v) {
  return 0.5f * v * (1.0f + erf_fast(v * 0.70710678118654752440f));
}

// tanh-form gelu: x*sigmoid(2*0.79788456*(x+0.044715 x^3)) as
// x - x/(exp2(z)+1), z = 2.3022077*x*(1+0.044715 x^2).
// |err vs erf-gelu| ~3e-4 abs — below bf16 storage quantum downstream.
__device__ __forceinline__ float gelu_tanh(float x) {
  const float x2 = x * x;
  const float u = fmaf(0.044715f, x2, 1.0f);
  const float z = x * u * 2.3022077f;
  const float e = exp2f(z);
  const float r = __builtin_amdgcn_rcpf(e + 1.0f);
  return fmaf(-x, r, x);
}

__device__ __forceinline__ u16 f2bf(float f) {  // RNE fp32 -> bf16 bits
  unsigned u = __float_as_uint(f);
  u = (u + 0x7FFFu + ((u >> 16) & 1u)) >> 16;
  return (u16)u;
}
__device__ __forceinline__ float bf2f(u16 h) {
  return __uint_as_float(((unsigned)h) << 16);
}

// packed RNE f32x2 -> bf16x2 (single instruction; same rounding as f2bf on
// finite values)
__device__ __forceinline__ unsigned cvt_pk_bf16(float lo, float hi) {
  unsigned r;
  asm("v_cvt_pk_bf16_f32 %0, %1, %2" : "=v"(r) : "v"(lo), "v"(hi));
  return r;
}

__device__ __forceinline__ void waveRed2(float& s, float& s2) {
#pragma unroll
  for (int m = 1; m < 64; m <<= 1) {
    s += __shfl_xor(s, m);
    s2 += __shfl_xor(s2, m);
  }
}

// ---------------- fused prep: nvphi(+stats) + converts + router-LN ----------------
__global__ __launch_bounds__(256) void k_prep(
    const float* __restrict__ nv, const float* __restrict__ pW1,
    const float* __restrict__ pb1, float* __restrict__ nvphi,
    float* __restrict__ nvstats, const float* __restrict__ pW2,
    u16* __restrict__ pW2T, const float* __restrict__ rW1,
    u16* __restrict__ rW1T, const float* __restrict__ rW2,
    u16* __restrict__ rW2T, const float* __restrict__ Wr2,
    u16* __restrict__ Wr2b, const float* __restrict__ x,
    const float* __restrict__ rn_g, const float* __restrict__ rn_b,
    float* __restrict__ xln) {
  __shared__ float nvs[128];
  __shared__ float red[12];
  const int b = blockIdx.x, tid = threadIdx.x;
  if (b < 2048) {
    const int n = b;
    if (tid < 128) nvs[tid] = nv[n * 128 + tid];
    __syncthreads();
    float s = pb1[tid];
#pragma unroll 4
    for (int i = 0; i < 128; ++i) s = fmaf(nvs[i], pW1[i * 256 + tid], s);
    nvphi[n * 256 + tid] = s;
    // row stats for analytic LN1 in k_phi: mean(nv), mean(nv^2), mean(nv*w)
    const float wv_ = pW1[128 * 256 + tid];
    float a1 = s, a2 = s * s, a3 = s * wv_;
#pragma unroll
    for (int m = 1; m < 64; m <<= 1) {
      a1 += __shfl_xor(a1, m);
      a2 += __shfl_xor(a2, m);
      a3 += __shfl_xor(a3, m);
    }
    if ((tid & 63) == 0) {
      red[(tid >> 6) * 3 + 0] = a1;
      red[(tid >> 6) * 3 + 1] = a2;
      red[(tid >> 6) * 3 + 2] = a3;
    }
    __syncthreads();
    if (tid < 3) {
      const float v = red[tid] + red[3 + tid] + red[6 + tid] + red[9 + tid];
      nvstats[n * 4 + tid] = v * (1.f / 256.f);
    } else if (tid == 3) {
      nvstats[n * 4 + 3] = 0.f;
    }
  } else if (b < 2304) {
    const int n = b - 2048;
    pW2T[n * 256 + tid] = f2bf(pW2[tid * 256 + n]);
  } else if (b < 2816) {
    const int n = b - 2304;
    if (tid < 256) rW1T[(size_t)n * 256 + tid] = f2bf(rW1[(size_t)tid * 512 + n]);
  } else if (b < 3328) {
    const int n = b - 2816;
    for (int k = tid; k < 512; k += 256)
      rW2T[(size_t)n * 512 + k] = f2bf(rW2[(size_t)k * 512 + n]);
  } else if (b < 7424) {
    const int i = (b - 3328) * 256 + tid;
    Wr2b[i] = f2bf(Wr2[i]);
  } else {
    const int t = b - 7424;
    const float v0 = x[(size_t)t * 512 + tid];
    const float v1 = x[(size_t)t * 512 + 256 + tid];
    float s = v0 + v1, s2 = v0 * v0 + v1 * v1;
    waveRed2(s, s2);
    if ((tid & 63) == 0) { red[(tid >> 6) * 2] = s; red[(tid >> 6) * 2 + 1] = s2; }
    __syncthreads();
    s = red[0] + red[2] + red[4] + red[6];
    s2 = red[1] + red[3] + red[5] + red[7];
    const float mu = s * (1.f / 512.f);
    const float var = fmaxf(s2 * (1.f / 512.f) - mu * mu, 0.f);
    const float rstd = 1.f / sqrtf(var + 1e-5f);
    xln[(size_t)t * 512 + tid] = (v0 - mu) * rstd * rn_g[tid] + rn_b[tid];
    xln[(size_t)t * 512 + 256 + tid] =
        (v1 - mu) * rstd * rn_g[tid + 256] + rn_b[tid + 256];
  }
}

// ---------------- 128x128 fp32 GEMM, C = act(A[M,K] @ B[N,K]^T) ----------------
template <int GMODE, bool BF16OUT>
__global__ __launch_bounds__(256) void gemm8f(const float* __restrict__ A,
                                              const float* __restrict__ B,
                                              float* __restrict__ C,
                                              u16* __restrict__ Cb, int M,
                                              int N, int K) {
  __shared__ float As[16][132];
  __shared__ float Bs[16][132];
  const int tid = threadIdx.x;
  const int tm = tid >> 4, tn = tid & 15;
  const int m0 = blockIdx.y * 128, n0 = blockIdx.x * 128;
  const int sr = tid >> 1, sk = (tid & 1) * 8;
  const float* gA = &A[(size_t)(m0 + sr) * K + sk];
  const float* gB = &B[(size_t)(n0 + sr) * K + sk];
  float acc[8][8] = {};
  for (int k0 = 0; k0 < K; k0 += 16) {
    const float4 a0 = *(const float4*)&gA[k0];
    const float4 a1 = *(const float4*)&gA[k0 + 4];
    const float4 b0 = *(const float4*)&gB[k0];
    const float4 b1 = *(const float4*)&gB[k0 + 4];
    __syncthreads();
    As[sk + 0][sr] = a0.x; As[sk + 1][sr] = a0.y; As[sk + 2][sr] = a0.z; As[sk + 3][sr] = a0.w;
    As[sk + 4][sr] = a1.x; As[sk + 5][sr] = a1.y; As[sk + 6][sr] = a1.z; As[sk + 7][sr] = a1.w;
    Bs[sk + 0][sr] = b0.x; Bs[sk + 1][sr] = b0.y; Bs[sk + 2][sr] = b0.z; Bs[sk + 3][sr] = b0.w;
    Bs[sk + 4][sr] = b1.x; Bs[sk + 5][sr] = b1.y; Bs[sk + 6][sr] = b1.z; Bs[sk + 7][sr] = b1.w;
    __syncthreads();
#pragma unroll
    for (int k = 0; k < 16; ++k) {
      float a[8], b[8];
      *(float4*)&a[0] = *(const float4*)&As[k][tm * 8];
      *(float4*)&a[4] = *(const float4*)&As[k][tm * 8 + 4];
      *(float4*)&b[0] = *(const float4*)&Bs[k][tn * 8];
      *(float4*)&b[4] = *(const float4*)&Bs[k][tn * 8 + 4];
#pragma unroll
      for (int i = 0; i < 8; ++i)
#pragma unroll
        for (int j = 0; j < 8; ++j) acc[i][j] = fmaf(a[i], b[j], acc[i][j]);
    }
  }
#pragma unroll
  for (int i = 0; i < 8; ++i) {
    float4 o0, o1;
    float* p0 = (float*)&o0;
    float* p1 = (float*)&o1;
#pragma unroll
    for (int j = 0; j < 4; ++j) {
      float xv = acc[i][j], yv = acc[i][j + 4];
      if (GMODE == 1) { xv = gelu_fast(xv); yv = gelu_fast(yv); }
      if (GMODE == 2) { xv = geluf(xv); yv = geluf(yv); }
      p0[j] = xv; p1[j] = yv;
    }
    const size_t off = (size_t)(m0 + tm * 8 + i) * N + n0 + tn * 8;
    *(float4*)&C[off] = o0;
    *(float4*)&C[off + 4] = o1;
    if (BF16OUT) {
      ushort4 u0, u1;
      u0.x = f2bf(p0[0]); u0.y = f2bf(p0[1]); u0.z = f2bf(p0[2]); u0.w = f2bf(p0[3]);
      u1.x = f2bf(p1[0]); u1.y = f2bf(p1[1]); u1.z = f2bf(p1[2]); u1.w = f2bf(p1[3]);
      *(ushort4*)&Cb[off] = u0;
      *(ushort4*)&Cb[off + 4] = u1;
    }
  }
}

// ---------------- MFMA GEMM: C = act(A[M,K] @ B[N,K]^T + bias) ----------------
template <int GMODE, bool BIAS, int OUT>
__global__ __launch_bounds__(256) void gemm_mf(const u16* __restrict__ Ahi,
                                               const u16* __restrict__ Bhi,
                                               const float* __restrict__ bias,
                                               void* __restrict__ Cp, int M,
                                               int N, int K) {
  constexpr int ASZ = 64 * 40;
  constexpr int BSZ = 128 * 40;
  __shared__ __align__(16) u16 smem[ASZ + BSZ];
  u16* sAh = smem;
  u16* sBh = smem + ASZ;

  const int tid = threadIdx.x;
  const int w = tid >> 6, lane = tid & 63;
  const int q = lane >> 4, c = lane & 15;
  const int m0 = blockIdx.y * 64, n0 = blockIdx.x * 128;
  const int ra = tid >> 2, ka = (tid & 3) * 8;
  const int rb = tid >> 1, kb = (tid & 1) * 16;
  const u16* gAh = Ahi + (size_t)(m0 + ra) * K + ka;
  const u16* gBh = Bhi + (size_t)(n0 + rb) * K + kb;

  f32x4 acc[8];
#pragma unroll
  for (int ct = 0; ct < 8; ++ct) {
    const float bv = BIAS ? bias[n0 + ct * 16 + c] : 0.f;
    acc[ct] = (f32x4){bv, bv, bv, bv};
  }

  for (int k0 = 0; k0 < K; k0 += 32) {
    const i32x4 vah = *(const i32x4*)(gAh + k0);
    const i32x4 vbh0 = *(const i32x4*)(gBh + k0);
    const i32x4 vbh1 = *(const i32x4*)(gBh + k0 + 8);
    __syncthreads();
    *(i32x4*)&sAh[ra * 40 + ka] = vah;
    *(i32x4*)&sBh[rb * 40 + kb] = vbh0;
    *(i32x4*)&sBh[rb * 40 + kb + 8] = vbh1;
    __syncthreads();
    const int abase = (w * 16 + c) * 40 + q * 8;
    const short8 ah = *(const short8*)&sAh[abase];
#pragma unroll
    for (int ct = 0; ct < 8; ++ct) {
      const int bbase = (ct * 16 + c) * 40 + q * 8;
      const short8 bh = *(const short8*)&sBh[bbase];
      acc[ct] = __builtin_amdgcn_mfma_f32_16x16x32_bf16(ah, bh, acc[ct], 0, 0, 0);
    }
  }
#pragma unroll
  for (int ct = 0; ct < 8; ++ct) {
#pragma unroll
    for (int reg = 0; reg < 4; ++reg) {
      float v = acc[ct][reg];
      if (GMODE == 1) v = gelu_fast(v);
      const size_t off = (size_t)(m0 + w * 16 + q * 4 + reg) * N + n0 + ct * 16 + c;
      if (OUT == 0) ((float*)Cp)[off] = v;
      else          ((u16*)Cp)[off] = f2bf(v);
    }
  }
}

// ---------------- fused: top-64 (approx+exact rescore) THEN act ----------------
__global__ __launch_bounds__(256) void k_topk_act(
    const u16* __restrict__ scoresb, const float* __restrict__ h,
    const float* __restrict__ Wr2, const float* __restrict__ x,
    const float* __restrict__ W_in, int* __restrict__ idxout,
    float* __restrict__ act) {
  __shared__ float hs[512];
  __shared__ int redc[2][4];
  __shared__ int cand[160];
  __shared__ float cex[160];
  __shared__ int selidx[64];
  __shared__ unsigned ccnt;
  const int t = blockIdx.x, tid = threadIdx.x;
  hs[tid] = h[(size_t)t * 512 + tid];
  hs[tid + 256] = h[(size_t)t * 512 + 256 + tid];
  unsigned key[8];
#pragma unroll
  for (int j = 0; j < 8; ++j) {
    const unsigned u = (unsigned)scoresb[(size_t)t * 2048 + tid + 256 * j];
    key[j] = (u & 0x8000u) ? (0xFFFFu & ~u) : (u | 0x8000u);
  }
  if (tid == 0) ccnt = 0u;
  // approx radix select (16 bits, 1 barrier/iter via double buffer)
  unsigned lo = 0u, hi = 0xFFFFu;
  int pb = 0;
  while (lo < hi) {
    const unsigned mid = (lo + hi + 1u) >> 1;
    int c = 0;
#pragma unroll
    for (int j = 0; j < 8; ++j) c += (key[j] >= mid);
#pragma unroll
    for (int m = 1; m < 64; m <<= 1) c += __shfl_xor(c, m);
    if ((tid & 63) == 0) redc[pb][tid >> 6] = c;
    __syncthreads();
    const int total = redc[pb][0] + redc[pb][1] + redc[pb][2] + redc[pb][3];
    if (total >= 96) lo = mid; else hi = mid - 1;
    pb ^= 1;
  }
#pragma unroll
  for (int j = 0; j < 8; ++j) {
    if (key[j] >= lo) {
      const unsigned pos = atomicAdd(&ccnt, 1u);
      if (pos < 160u) cand[pos] = tid + 256 * j;
    }
  }
  __syncthreads();
  const int cnt = (int)(ccnt < 160u ? ccnt : 160u);
  // exact fp32 rescore of candidates (lane-consecutive, coalesced)
  const int wv = tid >> 6, l = tid & 63;
  for (int ci = wv; ci < cnt; ci += 4) {
    const float* Wr = Wr2 + (size_t)cand[ci] * 512;
    float s = 0.f;
#pragma unroll
    for (int j = 0; j < 8; ++j) s = fmaf(Wr[l + 64 * j], hs[l + 64 * j], s);
#pragma unroll
    for (int m = 1; m < 64; m <<= 1) s += __shfl_xor(s, m);
    if (l == 0) cex[ci] = s;
  }
  __syncthreads();
  // rank-based exact top-64 (no barriers in loop; LDS broadcast reads)
  if (tid < cnt) {
    const float my = cex[tid];
    const int myi = cand[tid];
    int rank = 0;
    for (int j = 0; j < cnt; ++j) {
      const float oj = cex[j];
      const int oi = cand[j];
      rank += (oj > my) || (oj == my && oi < myi);
    }
    if (rank < 64) {
      selidx[rank] = myi;
      idxout[(size_t)t * 64 + rank] = myi;
    }
  }
  __syncthreads();
  // ---- Part 2: act (reuse hs for x) ----
  hs[tid] = x[(size_t)t * 512 + tid];
  hs[tid + 256] = x[(size_t)t * 512 + 256 + tid];
  __syncthreads();
  const float4 xa = *(const float4*)&hs[l * 8];
  const float4 xb = *(const float4*)&hs[l * 8 + 4];
  for (int qq = 0; qq < 16; ++qq) {
    const int k = wv * 16 + qq;
    const int n = selidx[k];
    const float* Wr = W_in + (size_t)n * 512 + l * 8;
    const float4 wa = *(const float4*)Wr;
    const float4 wb = *(const float4*)(Wr + 4);
    float s = wa.x * xa.x;
    s = fmaf(wa.y, xa.y, s); s = fmaf(wa.z, xa.z, s); s = fmaf(wa.w, xa.w, s);
    s = fmaf(wb.x, xb.x, s); s = fmaf(wb.y, xb.y, s);
    s = fmaf(wb.z, xb.z, s); s = fmaf(wb.w, xb.w, s);
#pragma unroll
    for (int m = 1; m < 64; m <<= 1) s += __shfl_xor(s, m);
    if (l == 0) act[(size_t)t * 64 + k] = gelu_fast(s);
  }
}

// ---------------- fused phi + rho-LN (one token per block) ----------------
// R16: (a) tanh-form gelu in Phase A (8 ops vs 16, err ~3e-4 << bf16
// quantum); (b) per-wave direct idx/act loads kill barrier B1 + LDS; (c)
// Phase-A rd+1 prefetch of nvstats/nvphi; (d) Phase-B double-buffered
// b-fragment prefetch at distance 2, first loads issued before the barrier.
__global__ __launch_bounds__(256, 4) void k_phi(
    const float* __restrict__ nvphi, const float* __restrict__ nvstats,
    const float* __restrict__ pW1, const float* __restrict__ pln1_g,
    const float* __restrict__ pln1_b, const u16* __restrict__ pW2T,
    const float* __restrict__ pb2, const float* __restrict__ pln2_g,
    const float* __restrict__ pln2_b, const int* __restrict__ idx,
    const float* __restrict__ act, const float* __restrict__ rln_g,
    const float* __restrict__ rln_b, u16* __restrict__ rh) {
  __shared__ __align__(16) u16 h1s[64 * 264];  // 33792 B; Phase C aliases as float scratch
  __shared__ float rowstats[64 * 2];           // {mu, rstd} per h2 row
  __shared__ float red[8];
  const int tid = threadIdx.x;
  const int t = blockIdx.x;
  const int w = tid >> 6, lane = tid & 63;
  const int q = lane >> 4, c = lane & 15;
  // ---- Phase A: h1 = bf16(gelu(LN1(nvphi[n] + act*pW1[128,:]))) ----
  {
    // wave-local idx/act (p = w*16+rd*4+q is wave-private -> no barrier)
    int n_pre[4];
    float a_pre[4];
#pragma unroll
    for (int rd = 0; rd < 4; ++rd) {
      n_pre[rd] = idx[(size_t)t * 64 + w * 16 + rd * 4 + q];
      a_pre[rd] = act[(size_t)t * 64 + w * 16 + rd * 4 + q];
    }
    f32x4 w4[4], g1[4], b1[4];
#pragma unroll
    for (int j = 0; j < 4; ++j) {
      w4[j] = *(const f32x4*)&pW1[128 * 256 + c * 16 + j * 4];
      g1[j] = *(const f32x4*)&pln1_g[c * 16 + j * 4];
      b1[j] = *(const f32x4*)&pln1_b[c * 16 + j * 4];
    }
    // global stats of the act-row w (same for all rows): mean, mean-square
    float sw = 0.f, sw2 = 0.f;
#pragma unroll
    for (int j = 0; j < 4; ++j)
#pragma unroll
      for (int u = 0; u < 4; ++u) {
        sw += w4[j][u];
        sw2 = fmaf(w4[j][u], w4[j][u], sw2);
      }
#pragma unroll
    for (int m = 1; m < 16; m <<= 1) {
      sw += __shfl_xor(sw, m);
      sw2 += __shfl_xor(sw2, m);
    }
    const float mw = sw * (1.f / 256.f), e2w = sw2 * (1.f / 256.f);
    f32x4 stc = *(const f32x4*)&nvstats[n_pre[0] * 4];  // {mu_nv,E2_nv,Enw,0}
    f32x4 nvc[4];
#pragma unroll
    for (int j = 0; j < 4; ++j)
      nvc[j] = *(const f32x4*)&nvphi[(size_t)n_pre[0] * 256 + c * 16 + j * 4];
#pragma unroll
    for (int rd = 0; rd < 4; ++rd) {
      f32x4 stn;
      f32x4 nvn[4];
      if (rd < 3) {  // prefetch next rd during this rd's gelu chain
        stn = *(const f32x4*)&nvstats[n_pre[rd + 1] * 4];
#pragma unroll
        for (int j = 0; j < 4; ++j)
          nvn[j] = *(const f32x4*)&nvphi[(size_t)n_pre[rd + 1] * 256 + c * 16 + j * 4];
      }
      const int p = w * 16 + rd * 4 + q;
      const float a = a_pre[rd];
      const float mu = fmaf(a, mw, stc.x);
      const float e2 = fmaf(a * a, e2w, fmaf(a + a, stc.z, stc.y));
      const float var = fmaxf(e2 - mu * mu, 0.f);
      const float rstd = 1.f / sqrtf(var + 1e-5f);
      const float nmr = -mu * rstd;
      unsigned pk[8];
#pragma unroll
      for (int j = 0; j < 4; ++j) {
        float hh[4];
#pragma unroll
        for (int u = 0; u < 4; ++u) {
          const float v = fmaf(a, w4[j][u], nvc[j][u]);
          const float tt = fmaf(v, rstd, nmr);
          hh[u] = gelu_tanh(fmaf(tt, g1[j][u], b1[j][u]));
        }
        pk[j * 2] = cvt_pk_bf16(hh[0], hh[1]);
        pk[j * 2 + 1] = cvt_pk_bf16(hh[2], hh[3]);
      }
      *(i32x4*)&h1s[p * 264 + c * 16] = (i32x4){(int)pk[0], (int)pk[1], (int)pk[2], (int)pk[3]};
      *(i32x4*)&h1s[p * 264 + c * 16 + 8] = (i32x4){(int)pk[4], (int)pk[5], (int)pk[6], (int)pk[7]};
      if (rd < 3) {
        stc = stn;
#pragma unroll
        for (int j = 0; j < 4; ++j) nvc[j] = nvn[j];
      }
    }
  }
  // ---- Phase B: acc[mt][nt] covers rows mt*16+q*4+reg, cols w*64+nt*16+c ----
  const u16* Bb = pW2T + ((size_t)(w * 64 + c) << 8) + q * 8;
  short8 be[4], bo[4];  // double-buffered b-fragments (even/odd ks)
#pragma unroll
  for (int nt = 0; nt < 4; ++nt) be[nt] = *(const short8*)&Bb[nt * 4096];
#pragma unroll
  for (int nt = 0; nt < 4; ++nt) bo[nt] = *(const short8*)&Bb[nt * 4096 + 32];
  f32x4 acc[4][4];
#pragma unroll
  for (int nt = 0; nt < 4; ++nt) {
    const float bz = pb2[w * 64 + nt * 16 + c];
#pragma unroll
    for (int mt = 0; mt < 4; ++mt) acc[mt][nt] = (f32x4){bz, bz, bz, bz};
  }
  __syncthreads();  // B2 (h1s is read cross-wave below)
#pragma unroll
  for (int ks2 = 0; ks2 < 4; ++ks2) {
    {  // even ks = 2*ks2
      short8 av[4];
#pragma unroll
      for (int mt = 0; mt < 4; ++mt)
        av[mt] = *(const short8*)&h1s[(mt * 16 + c) * 264 + ks2 * 64 + q * 8];
#pragma unroll
      for (int mt = 0; mt < 4; ++mt)
#pragma unroll
        for (int nt = 0; nt < 4; ++nt)
          acc[mt][nt] =
              __builtin_amdgcn_mfma_f32_16x16x32_bf16(av[mt], be[nt], acc[mt][nt], 0, 0, 0);
      if (ks2 < 3) {  // prefetch ks = 2*ks2+2
#pragma unroll
        for (int nt = 0; nt < 4; ++nt)
          be[nt] = *(const short8*)&Bb[nt * 4096 + ks2 * 64 + 64];
      }
    }
    {  // odd ks = 2*ks2+1
      short8 av[4];
#pragma unroll
      for (int mt = 0; mt < 4; ++mt)
        av[mt] = *(const short8*)&h1s[(mt * 16 + c) * 264 + ks2 * 64 + 32 + q * 8];
#pragma unroll
      for (int mt = 0; mt < 4; ++mt)
#pragma unroll
        for (int nt = 0; nt < 4; ++nt)
          acc[mt][nt] =
              __builtin_amdgcn_mfma_f32_16x16x32_bf16(av[mt], bo[nt], acc[mt][nt], 0, 0, 0);
      if (ks2 < 3) {  // prefetch ks = 2*ks2+3
#pragma unroll
        for (int nt = 0; nt < 4; ++nt)
          bo[nt] = *(const short8*)&Bb[nt * 4096 + ks2 * 64 + 96];
      }
    }
  }
  __syncthreads();  // B3 (all waves done reading h1s; safe to alias)
  // ---- Phase C: LN2 stats via LDS transpose reduce ----
  // sbuf/s2buf: [64 rows][66] floats each (stride 66 -> 2-way-max write
  // conflicts, even 8/bank reads). 2*64*66*4 = 33792 B = h1s exactly.
  float* sbuf = (float*)h1s;
  float* s2buf = sbuf + 64 * 66;
#pragma unroll
  for (int mt = 0; mt < 4; ++mt)
#pragma unroll
    for (int reg = 0; reg < 4; ++reg) {
      const float v0 = acc[mt][0][reg], v1 = acc[mt][1][reg];
      const float v2 = acc[mt][2][reg], v3 = acc[mt][3][reg];
      const float s = (v0 + v1) + (v2 + v3);
      float s2 = v0 * v0;
      s2 = fmaf(v1, v1, s2);
      s2 = fmaf(v2, v2, s2);
      s2 = fmaf(v3, v3, s2);
      const int r = mt * 16 + q * 4 + reg;
      sbuf[r * 66 + w * 16 + c] = s;
      s2buf[r * 66 + w * 16 + c] = s2;
    }
  __syncthreads();  // B4
  {
    const int r = tid >> 2, seg = tid & 3;
    const float* rp = &sbuf[r * 66 + seg * 16];
    const float* rp2 = &s2buf[r * 66 + seg * 16];
    float ss = 0.f, ss2 = 0.f;
#pragma unroll
    for (int j = 0; j < 8; ++j) {
      const f32x2 u = *(const f32x2*)&rp[j * 2];
      const f32x2 u2 = *(const f32x2*)&rp2[j * 2];
      ss += u[0] + u[1];
      ss2 += u2[0] + u2[1];
    }
    ss += __shfl_xor(ss, 1);
    ss2 += __shfl_xor(ss2, 1);
    ss += __shfl_xor(ss, 2);
    ss2 += __shfl_xor(ss2, 2);
    if (seg == 0) {
      const float mu = ss * (1.f / 256.f);
      const float var = fmaxf(ss2 * (1.f / 256.f) - mu * mu, 0.f);
      const float rstd = 1.f / sqrtf(var + 1e-5f);
      rowstats[r * 2] = mu;
      rowstats[r * 2 + 1] = rstd;
    }
  }
  __syncthreads();  // B5
  // ---- LN2 apply + k-sum ----
  float g2v[4], b2v[4], aggl[4];
#pragma unroll
  for (int nt = 0; nt < 4; ++nt) {
    g2v[nt] = pln2_g[w * 64 + nt * 16 + c];
    b2v[nt] = pln2_b[w * 64 + nt * 16 + c];
    aggl[nt] = 16.f * b2v[nt];  // b2 added once per row, 16 rows per lane
  }
#pragma unroll
  for (int mt = 0; mt < 4; ++mt)
#pragma unroll
    for (int reg = 0; reg < 4; ++reg) {
      const int r = mt * 16 + q * 4 + reg;
      const f32x2 mr = *(const f32x2*)&rowstats[r * 2];
      const float nmr = -mr[0] * mr[1];
#pragma unroll
      for (int nt = 0; nt < 4; ++nt) {
        const float tt = fmaf(acc[mt][nt][reg], mr[1], nmr);
        aggl[nt] = fmaf(tt, g2v[nt], aggl[nt]);
      }
    }
  // sum over the q-partitioned rows -> full 64-row aggregate per column
  float* aggb = sbuf;  // words 0..255 dead after B5 reads
#pragma unroll
  for (int nt = 0; nt < 4; ++nt) {
    float vs = aggl[nt];
    vs += __shfl_xor(vs, 16);
    vs += __shfl_xor(vs, 32);
    if (q == 0) aggb[w * 64 + nt * 16 + c] = vs;
  }
  __syncthreads();  // B6
  // ---- fused rho-LN over 256 ----
  const float v = aggb[tid];
  float s = v, s2 = v * v;
  waveRed2(s, s2);
  if ((tid & 63) == 0) { red[(tid >> 6) * 2] = s; red[(tid >> 6) * 2 + 1] = s2; }
  __syncthreads();  // B7
  s = red[0] + red[2] + red[4] + red[6];
  s2 = red[1] + red[3] + red[5] + red[7];
  const float mu = s * (1.f / 256.f);
  const float var = fmaxf(s2 * (1.f / 256.f) - mu * mu, 0.f);
  const float rstd = 1.f / sqrtf(var + 1e-5f);
  rh[(size_t)t * 256 + tid] = f2bf((v - mu) * rstd * rln_g[tid] + rln_b[tid]);
}

// ---------------- launch ----------------
extern "C" void kernel_launch(void* const* d_in, const int* in_sizes, int n_in,
                              void* d_out, int out_size, void* d_ws, size_t ws_size,
                              hipStream_t stream) {
  const float* x = (const float*)d_in[0];
  const float* W_in = (const float*)d_in[1];
  const float* nv = (const float*)d_in[2];
  const float* Wr1 = (const float*)d_in[3];
  const float* Wr2 = (const float*)d_in[4];
  const float* rn_g = (const float*)d_in[5];
  const float* rn_b = (const float*)d_in[6];
  const float* pW1 = (const float*)d_in[7];
  const float* pb1 = (const float*)d_in[8];
  const float* pln1_g = (const float*)d_in[9];
  const float* pln1_b = (const float*)d_in[10];
  const float* pW2 = (const float*)d_in[11];
  const float* pb2 = (const float*)d_in[12];
  const float* pln2_g = (const float*)d_in[13];
  const float* pln2_b = (const float*)d_in[14];
  const float* rln_g = (const float*)d_in[15];
  const float* rln_b = (const float*)d_in[16];
  const float* rW1 = (const float*)d_in[17];
  const float* rb1 = (const float*)d_in[18];
  const float* rW2 = (const float*)d_in[19];
  const float* rb2 = (const float*)d_in[20];
  float* out = (float*)d_out;
  const int T = in_sizes[0] / 512;  // 4096

  float* ws = (float*)d_ws;
  float* xln = ws;    ws += (size_t)T * 512;
  float* h = ws;      ws += (size_t)T * 512;
  float* nvphi = ws;  ws += (size_t)2048 * 256;
  float* nvstats = ws; ws += (size_t)2048 * 4;
  float* actb = ws;   ws += (size_t)T * 64;
  int* idx = (int*)ws;   ws += (size_t)T * 64;
  u16* scoresb = (u16*)ws; ws += (size_t)T * 2048 / 2;
  u16* hb = (u16*)ws;    ws += (size_t)T * 512 / 2;
  u16* Wr2b = (u16*)ws;  ws += (size_t)2048 * 512 / 2;
  u16* pW2T = (u16*)ws;  ws += (size_t)2048 * 256 / 2;
  u16* rh = (u16*)ws;    ws += (size_t)T * 256 / 2;
  u16* t1b = (u16*)ws;   ws += (size_t)T * 512 / 2;
  u16* rW1T = (u16*)ws;  ws += (size_t)512 * 256 / 2;
  u16* rW2T = (u16*)ws;  ws += (size_t)512 * 512 / 2;

  k_prep<<<7424 + T, 256, 0, stream>>>(nv, pW1, pb1, nvphi, nvstats, pW2, pW2T,
                                       rW1, rW1T, rW2, rW2T, Wr2, Wr2b, x, rn_g,
                                       rn_b, xln);
  gemm8f<2, true><<<dim3(512 / 128, T / 128), 256, 0, stream>>>(
      xln, Wr1, h, hb, T, 512, 512);
  gemm_mf<0, false, 1><<<dim3(2048 / 128, T / 64), 256, 0, stream>>>(
      hb, Wr2b, nullptr, scoresb, T, 2048, 512);
  k_topk_act<<<T, 256, 0, stream>>>(scoresb, h, Wr2, x, W_in, idx, actb);
  k_phi<<<T, 256, 0, stream>>>(nvphi, nvstats, pW1, pln1_g, pln1_b, pW2T, pb2,
                               pln2_g, pln2_b, idx, actb, rln_g, rln_b, rh);
  gemm_mf<1, true, 1><<<dim3(512 / 128, T / 64), 256, 0, stream>>>(
      rh, rW1T, rb1, t1b, T, 512, 256);
  gemm_mf<0, true, 0><<<dim3(512 / 128, T / 64), 256, 0, stream>>>(
      t1b, rW2T, rb2, out, T, 512, 512);
}

// Round 4
// 392.668 us; speedup vs baseline: 1.1344x; 1.0432x over previous
//
#include <hip/hip_runtime.h>
#include <cstdint>
#include <cstddef>

typedef unsigned short u16;
typedef float f32x4 __attribute__((ext_vector_type(4)));
typedef float f32x2 __attribute__((ext_vector_type(2)));
typedef short short8 __attribute__((ext_vector_type(8)));
typedef int i32x4 __attribute__((ext_vector_type(4)));

// ---------------- helpers ----------------

__device__ __forceinline__ float geluf(float v) {  // exact (libm erff)
  return 0.5f * v * (1.0f + erff(v * 0.70710678118654752440f));
}

// Abramowitz-Stegun 7.1.26: |err| <= 1.5e-7 abs.
__device__ __forceinline__ float erf_fast(float x) {
  const float ax = fabsf(x);
  const float t = __builtin_amdgcn_rcpf(fmaf(0.3275911f, ax, 1.0f));
  float p = fmaf(1.061405429f, t, -1.453152027f);
  p = fmaf(p, t, 1.421413741f);
  p = fmaf(p, t, -0.284496736f);
  p = fmaf(p, t, 0.254829592f);
  p = p * t;
  const float e = __expf(-ax * ax);
  const float r = fmaf(-p, e, 1.0f);
  return copysignf(r, x);
}
__device__ __forceinline__ float gelu_fast(float v) {
  return 0.5f * v * (1.0f + erf_fast(v * 0.70710678118654752440f));
}

// tanh-form gelu: |err vs erf-gelu| ~3e-4 abs — below bf16 storage quantum.
__device__ __forceinline__ float gelu_tanh(float x) {
  const float x2 = x * x;
  const float u = fmaf(0.044715f, x2, 1.0f);
  const float z = x * u * 2.3022077f;
  const float e = exp2f(z);
  const float r = __builtin_amdgcn_rcpf(e + 1.0f);
  return fmaf(-x, r, x);
}

__device__ __forceinline__ u16 f2bf(float f) {  // RNE fp32 -> bf16 bits
  unsigned u = __float_as_uint(f);
  u = (u + 0x7FFFu + ((u >> 16) & 1u)) >> 16;
  return (u16)u;
}
__device__ __forceinline__ float bf2f(u16 h) {
  return __uint_as_float(((unsigned)h) << 16);
}

__device__ __forceinline__ unsigned cvt_pk_bf16(float lo, float hi) {
  unsigned r;
  asm("v_cvt_pk_bf16_f32 %0, %1, %2" : "=v"(r) : "v"(lo), "v"(hi));
  return r;
}

__device__ __forceinline__ void waveRed2(float& s, float& s2) {
#pragma unroll
  for (int m = 1; m < 64; m <<= 1) {
    s += __shfl_xor(s, m);
    s2 += __shfl_xor(s2, m);
  }
}

// ---------------- fused prep: nvphi(+stats) + converts + router-LN ----------------
// R17: nvphi branch is 8 neurons/block (256 blocks) with LDS-transposed nv —
// pW1 L2 traffic drops 268MB -> 33MB and fma/thread rises 128 -> 1024.
__global__ __launch_bounds__(256) void k_prep(
    const float* __restrict__ nv, const float* __restrict__ pW1,
    const float* __restrict__ pb1, float* __restrict__ nvphi,
    float* __restrict__ nvstats, const float* __restrict__ pW2,
    u16* __restrict__ pW2T, const float* __restrict__ rW1,
    u16* __restrict__ rW1T, const float* __restrict__ rW2,
    u16* __restrict__ rW2T, const float* __restrict__ Wr2,
    u16* __restrict__ Wr2b, const float* __restrict__ x,
    const float* __restrict__ rn_g, const float* __restrict__ rn_b,
    float* __restrict__ xln) {
  __shared__ __align__(16) float sbuf[1536 + 96];
  const int b = blockIdx.x, tid = threadIdx.x;
  if (b < 256) {
    const int n0 = b * 8;
    // stage nv rows n0..n0+7 transposed: nvsT[i][k], stride 12 (f32x4-aligned)
#pragma unroll
    for (int j = 0; j < 4; ++j) {
      const int e = tid + j * 256;  // e = k*128 + i
      sbuf[(e & 127) * 12 + (e >> 7)] = nv[n0 * 128 + e];
    }
    __syncthreads();
    float acc[8] = {};
#pragma unroll 2
    for (int i = 0; i < 128; ++i) {
      const float wv_ = pW1[i * 256 + tid];
      const f32x4 nA = *(const f32x4*)&sbuf[i * 12];
      const f32x4 nB = *(const f32x4*)&sbuf[i * 12 + 4];
      acc[0] = fmaf(nA[0], wv_, acc[0]);
      acc[1] = fmaf(nA[1], wv_, acc[1]);
      acc[2] = fmaf(nA[2], wv_, acc[2]);
      acc[3] = fmaf(nA[3], wv_, acc[3]);
      acc[4] = fmaf(nB[0], wv_, acc[4]);
      acc[5] = fmaf(nB[1], wv_, acc[5]);
      acc[6] = fmaf(nB[2], wv_, acc[6]);
      acc[7] = fmaf(nB[3], wv_, acc[7]);
    }
    const float pb = pb1[tid];
    const float wact = pW1[128 * 256 + tid];
    float* redN = sbuf + 1536;  // [4 waves][8 kk][3 stats]
#pragma unroll
    for (int kk = 0; kk < 8; ++kk) {
      const float s = acc[kk] + pb;
      nvphi[(size_t)(n0 + kk) * 256 + tid] = s;
      float a1 = s, a2 = s * s, a3 = s * wact;
#pragma unroll
      for (int m = 1; m < 64; m <<= 1) {
        a1 += __shfl_xor(a1, m);
        a2 += __shfl_xor(a2, m);
        a3 += __shfl_xor(a3, m);
      }
      if ((tid & 63) == 0) {
        const int w4 = tid >> 6;
        redN[w4 * 24 + kk * 3 + 0] = a1;
        redN[w4 * 24 + kk * 3 + 1] = a2;
        redN[w4 * 24 + kk * 3 + 2] = a3;
      }
    }
    __syncthreads();
    if (tid < 24) {
      const int kk = tid / 3, st = tid - kk * 3;
      const float v = redN[tid] + redN[24 + tid] + redN[48 + tid] + redN[72 + tid];
      nvstats[(size_t)(n0 + kk) * 4 + st] = v * (1.f / 256.f);
    } else if (tid < 32) {
      nvstats[(size_t)(n0 + tid - 24) * 4 + 3] = 0.f;
    }
  } else if (b < 512) {
    const int n = b - 256;
    pW2T[n * 256 + tid] = f2bf(pW2[tid * 256 + n]);
  } else if (b < 1024) {
    const int n = b - 512;
    rW1T[(size_t)n * 256 + tid] = f2bf(rW1[(size_t)tid * 512 + n]);
  } else if (b < 1536) {
    const int n = b - 1024;
    for (int k = tid; k < 512; k += 256)
      rW2T[(size_t)n * 512 + k] = f2bf(rW2[(size_t)k * 512 + n]);
  } else if (b < 5632) {
    const int i = (b - 1536) * 256 + tid;
    Wr2b[i] = f2bf(Wr2[i]);
  } else {
    float* red = sbuf;
    const int t = b - 5632;
    const float v0 = x[(size_t)t * 512 + tid];
    const float v1 = x[(size_t)t * 512 + 256 + tid];
    float s = v0 + v1, s2 = v0 * v0 + v1 * v1;
    waveRed2(s, s2);
    if ((tid & 63) == 0) { red[(tid >> 6) * 2] = s; red[(tid >> 6) * 2 + 1] = s2; }
    __syncthreads();
    s = red[0] + red[2] + red[4] + red[6];
    s2 = red[1] + red[3] + red[5] + red[7];
    const float mu = s * (1.f / 512.f);
    const float var = fmaxf(s2 * (1.f / 512.f) - mu * mu, 0.f);
    const float rstd = 1.f / sqrtf(var + 1e-5f);
    xln[(size_t)t * 512 + tid] = (v0 - mu) * rstd * rn_g[tid] + rn_b[tid];
    xln[(size_t)t * 512 + 256 + tid] =
        (v1 - mu) * rstd * rn_g[tid + 256] + rn_b[tid + 256];
  }
}

// ---------------- 128x64 fp32 GEMM, C = act(A[M,K] @ B[N,K]^T) ----------------
// R17: retiled 128x128 -> 128x64 (grid 128 -> 256 blocks: fills all CUs) +
// register prefetch of k0+1 before the FMA cluster (hides L3/HBM latency
// under 1024 cy of FMA). Per-output k-summation order unchanged -> h is
// bit-identical (selection-critical for the exact rescore).
template <int GMODE, bool BF16OUT>
__global__ __launch_bounds__(256) void gemm8f(const float* __restrict__ A,
                                              const float* __restrict__ B,
                                              float* __restrict__ C,
                                              u16* __restrict__ Cb, int M,
                                              int N, int K) {
  __shared__ float As[16][132];
  __shared__ float Bs[16][68];
  const int tid = threadIdx.x;
  const int tm = tid >> 4, tn = tid & 15;
  const int m0 = blockIdx.y * 128, n0 = blockIdx.x * 64;
  const int sr = tid >> 1, sk = (tid & 1) * 8;    // A stage: 128 rows x 8 k
  const int srB = tid >> 2, skB = (tid & 3) * 4;  // B stage: 64 rows x 4 k
  const float* gA = &A[(size_t)(m0 + sr) * K + sk];
  const float* gB = &B[(size_t)(n0 + srB) * K + skB];
  float acc[8][4] = {};
  float4 a0 = *(const float4*)&gA[0];
  float4 a1 = *(const float4*)&gA[4];
  float4 b0 = *(const float4*)&gB[0];
  const int nk0 = K >> 4;
  for (int it = 0; it < nk0; ++it) {
    __syncthreads();
    As[sk + 0][sr] = a0.x; As[sk + 1][sr] = a0.y; As[sk + 2][sr] = a0.z; As[sk + 3][sr] = a0.w;
    As[sk + 4][sr] = a1.x; As[sk + 5][sr] = a1.y; As[sk + 6][sr] = a1.z; As[sk + 7][sr] = a1.w;
    Bs[skB + 0][srB] = b0.x; Bs[skB + 1][srB] = b0.y; Bs[skB + 2][srB] = b0.z; Bs[skB + 3][srB] = b0.w;
    __syncthreads();
    if (it + 1 < nk0) {
      const int k0 = (it + 1) * 16;
      a0 = *(const float4*)&gA[k0];
      a1 = *(const float4*)&gA[k0 + 4];
      b0 = *(const float4*)&gB[k0];
    }
#pragma unroll
    for (int k = 0; k < 16; ++k) {
      float a[8], bb[4];
      *(float4*)&a[0] = *(const float4*)&As[k][tm * 8];
      *(float4*)&a[4] = *(const float4*)&As[k][tm * 8 + 4];
      *(float4*)&bb[0] = *(const float4*)&Bs[k][tn * 4];
#pragma unroll
      for (int i = 0; i < 8; ++i)
#pragma unroll
        for (int j = 0; j < 4; ++j) acc[i][j] = fmaf(a[i], bb[j], acc[i][j]);
    }
  }
#pragma unroll
  for (int i = 0; i < 8; ++i) {
    float4 o0;
    float* p0 = (float*)&o0;
#pragma unroll
    for (int j = 0; j < 4; ++j) {
      float xv = acc[i][j];
      if (GMODE == 1) xv = gelu_fast(xv);
      if (GMODE == 2) xv = geluf(xv);
      p0[j] = xv;
    }
    const size_t off = (size_t)(m0 + tm * 8 + i) * N + n0 + tn * 4;
    *(float4*)&C[off] = o0;
    if (BF16OUT) {
      ushort4 u0;
      u0.x = f2bf(p0[0]); u0.y = f2bf(p0[1]); u0.z = f2bf(p0[2]); u0.w = f2bf(p0[3]);
      *(ushort4*)&Cb[off] = u0;
    }
  }
}

// ---------------- MFMA GEMM: C = act(A[M,K] @ B[N,K]^T + bias) ----------------
// R17: next-tile register prefetch issued before the MFMA cluster.
template <int GMODE, bool BIAS, int OUT>
__global__ __launch_bounds__(256) void gemm_mf(const u16* __restrict__ Ahi,
                                               const u16* __restrict__ Bhi,
                                               const float* __restrict__ bias,
                                               void* __restrict__ Cp, int M,
                                               int N, int K) {
  constexpr int ASZ = 64 * 40;
  constexpr int BSZ = 128 * 40;
  __shared__ __align__(16) u16 smem[ASZ + BSZ];
  u16* sAh = smem;
  u16* sBh = smem + ASZ;

  const int tid = threadIdx.x;
  const int w = tid >> 6, lane = tid & 63;
  const int q = lane >> 4, c = lane & 15;
  const int m0 = blockIdx.y * 64, n0 = blockIdx.x * 128;
  const int ra = tid >> 2, ka = (tid & 3) * 8;
  const int rb = tid >> 1, kb = (tid & 1) * 16;
  const u16* gAh = Ahi + (size_t)(m0 + ra) * K + ka;
  const u16* gBh = Bhi + (size_t)(n0 + rb) * K + kb;

  f32x4 acc[8];
#pragma unroll
  for (int ct = 0; ct < 8; ++ct) {
    const float bv = BIAS ? bias[n0 + ct * 16 + c] : 0.f;
    acc[ct] = (f32x4){bv, bv, bv, bv};
  }

  i32x4 vah = *(const i32x4*)(gAh);
  i32x4 vbh0 = *(const i32x4*)(gBh);
  i32x4 vbh1 = *(const i32x4*)(gBh + 8);
  const int nk0 = K >> 5;
  for (int it = 0; it < nk0; ++it) {
    __syncthreads();
    *(i32x4*)&sAh[ra * 40 + ka] = vah;
    *(i32x4*)&sBh[rb * 40 + kb] = vbh0;
    *(i32x4*)&sBh[rb * 40 + kb + 8] = vbh1;
    __syncthreads();
    if (it + 1 < nk0) {
      const int k0 = (it + 1) * 32;
      vah = *(const i32x4*)(gAh + k0);
      vbh0 = *(const i32x4*)(gBh + k0);
      vbh1 = *(const i32x4*)(gBh + k0 + 8);
    }
    const int abase = (w * 16 + c) * 40 + q * 8;
    const short8 ah = *(const short8*)&sAh[abase];
#pragma unroll
    for (int ct = 0; ct < 8; ++ct) {
      const int bbase = (ct * 16 + c) * 40 + q * 8;
      const short8 bh = *(const short8*)&sBh[bbase];
      acc[ct] = __builtin_amdgcn_mfma_f32_16x16x32_bf16(ah, bh, acc[ct], 0, 0, 0);
    }
  }
#pragma unroll
  for (int ct = 0; ct < 8; ++ct) {
#pragma unroll
    for (int reg = 0; reg < 4; ++reg) {
      float v = acc[ct][reg];
      if (GMODE == 1) v = gelu_fast(v);
      const size_t off = (size_t)(m0 + w * 16 + q * 4 + reg) * N + n0 + ct * 16 + c;
      if (OUT == 0) ((float*)Cp)[off] = v;
      else          ((u16*)Cp)[off] = f2bf(v);
    }
  }
}

// ---------------- fused: top-64 (approx+exact rescore) THEN act ----------------
__global__ __launch_bounds__(256) void k_topk_act(
    const u16* __restrict__ scoresb, const float* __restrict__ h,
    const float* __restrict__ Wr2, const float* __restrict__ x,
    const float* __restrict__ W_in, int* __restrict__ idxout,
    float* __restrict__ act) {
  __shared__ float hs[512];
  __shared__ int redc[2][4];
  __shared__ int cand[160];
  __shared__ float cex[160];
  __shared__ int selidx[64];
  __shared__ unsigned ccnt;
  const int t = blockIdx.x, tid = threadIdx.x;
  hs[tid] = h[(size_t)t * 512 + tid];
  hs[tid + 256] = h[(size_t)t * 512 + 256 + tid];
  unsigned key[8];
#pragma unroll
  for (int j = 0; j < 8; ++j) {
    const unsigned u = (unsigned)scoresb[(size_t)t * 2048 + tid + 256 * j];
    key[j] = (u & 0x8000u) ? (0xFFFFu & ~u) : (u | 0x8000u);
  }
  if (tid == 0) ccnt = 0u;
  // approx radix select (16 bits, 1 barrier/iter via double buffer)
  unsigned lo = 0u, hi = 0xFFFFu;
  int pb = 0;
  while (lo < hi) {
    const unsigned mid = (lo + hi + 1u) >> 1;
    int c = 0;
#pragma unroll
    for (int j = 0; j < 8; ++j) c += (key[j] >= mid);
#pragma unroll
    for (int m = 1; m < 64; m <<= 1) c += __shfl_xor(c, m);
    if ((tid & 63) == 0) redc[pb][tid >> 6] = c;
    __syncthreads();
    const int total = redc[pb][0] + redc[pb][1] + redc[pb][2] + redc[pb][3];
    if (total >= 96) lo = mid; else hi = mid - 1;
    pb ^= 1;
  }
#pragma unroll
  for (int j = 0; j < 8; ++j) {
    if (key[j] >= lo) {
      const unsigned pos = atomicAdd(&ccnt, 1u);
      if (pos < 160u) cand[pos] = tid + 256 * j;
    }
  }
  __syncthreads();
  const int cnt = (int)(ccnt < 160u ? ccnt : 160u);
  // exact fp32 rescore of candidates (lane-consecutive, coalesced)
  const int wv = tid >> 6, l = tid & 63;
#pragma unroll 2
  for (int ci = wv; ci < cnt; ci += 4) {
    const float* Wr = Wr2 + (size_t)cand[ci] * 512;
    float s = 0.f;
#pragma unroll
    for (int j = 0; j < 8; ++j) s = fmaf(Wr[l + 64 * j], hs[l + 64 * j], s);
#pragma unroll
    for (int m = 1; m < 64; m <<= 1) s += __shfl_xor(s, m);
    if (l == 0) cex[ci] = s;
  }
  __syncthreads();
  // rank-based exact top-64 (no barriers in loop; LDS broadcast reads)
  if (tid < cnt) {
    const float my = cex[tid];
    const int myi = cand[tid];
    int rank = 0;
    for (int j = 0; j < cnt; ++j) {
      const float oj = cex[j];
      const int oi = cand[j];
      rank += (oj > my) || (oj == my && oi < myi);
    }
    if (rank < 64) {
      selidx[rank] = myi;
      idxout[(size_t)t * 64 + rank] = myi;
    }
  }
  __syncthreads();
  // ---- Part 2: act (reuse hs for x) ----
  hs[tid] = x[(size_t)t * 512 + tid];
  hs[tid + 256] = x[(size_t)t * 512 + 256 + tid];
  __syncthreads();
  const float4 xa = *(const float4*)&hs[l * 8];
  const float4 xb = *(const float4*)&hs[l * 8 + 4];
#pragma unroll 2
  for (int qq = 0; qq < 16; ++qq) {
    const int k = wv * 16 + qq;
    const int n = selidx[k];
    const float* Wr = W_in + (size_t)n * 512 + l * 8;
    const float4 wa = *(const float4*)Wr;
    const float4 wb = *(const float4*)(Wr + 4);
    float s = wa.x * xa.x;
    s = fmaf(wa.y, xa.y, s); s = fmaf(wa.z, xa.z, s); s = fmaf(wa.w, xa.w, s);
    s = fmaf(wb.x, xb.x, s); s = fmaf(wb.y, xb.y, s);
    s = fmaf(wb.z, xb.z, s); s = fmaf(wb.w, xb.w, s);
#pragma unroll
    for (int m = 1; m < 64; m <<= 1) s += __shfl_xor(s, m);
    if (l == 0) act[(size_t)t * 64 + k] = gelu_fast(s);
  }
}

// ---------------- fused phi + rho-LN (one token per block) ----------------
// R16 (locked): analytic LN1 stats; tanh-gelu; per-wave idx/act loads;
// Phase-A rd+1 prefetch; Phase-B double-buffered b-fragment prefetch.
__global__ __launch_bounds__(256, 4) void k_phi(
    const float* __restrict__ nvphi, const float* __restrict__ nvstats,
    const float* __restrict__ pW1, const float* __restrict__ pln1_g,
    const float* __restrict__ pln1_b, const u16* __restrict__ pW2T,
    const float* __restrict__ pb2, const float* __restrict__ pln2_g,
    const float* __restrict__ pln2_b, const int* __restrict__ idx,
    const float* __restrict__ act, const float* __restrict__ rln_g,
    const float* __restrict__ rln_b, u16* __restrict__ rh) {
  __shared__ __align__(16) u16 h1s[64 * 264];  // 33792 B; Phase C aliases as float scratch
  __shared__ float rowstats[64 * 2];           // {mu, rstd} per h2 row
  __shared__ float red[8];
  const int tid = threadIdx.x;
  const int t = blockIdx.x;
  const int w = tid >> 6, lane = tid & 63;
  const int q = lane >> 4, c = lane & 15;
  // ---- Phase A: h1 = bf16(gelu(LN1(nvphi[n] + act*pW1[128,:]))) ----
  {
    int n_pre[4];
    float a_pre[4];
#pragma unroll
    for (int rd = 0; rd < 4; ++rd) {
      n_pre[rd] = idx[(size_t)t * 64 + w * 16 + rd * 4 + q];
      a_pre[rd] = act[(size_t)t * 64 + w * 16 + rd * 4 + q];
    }
    f32x4 w4[4], g1[4], b1[4];
#pragma unroll
    for (int j = 0; j < 4; ++j) {
      w4[j] = *(const f32x4*)&pW1[128 * 256 + c * 16 + j * 4];
      g1[j] = *(const f32x4*)&pln1_g[c * 16 + j * 4];
      b1[j] = *(const f32x4*)&pln1_b[c * 16 + j * 4];
    }
    float sw = 0.f, sw2 = 0.f;
#pragma unroll
    for (int j = 0; j < 4; ++j)
#pragma unroll
      for (int u = 0; u < 4; ++u) {
        sw += w4[j][u];
        sw2 = fmaf(w4[j][u], w4[j][u], sw2);
      }
#pragma unroll
    for (int m = 1; m < 16; m <<= 1) {
      sw += __shfl_xor(sw, m);
      sw2 += __shfl_xor(sw2, m);
    }
    const float mw = sw * (1.f / 256.f), e2w = sw2 * (1.f / 256.f);
    f32x4 stc = *(const f32x4*)&nvstats[n_pre[0] * 4];
    f32x4 nvc[4];
#pragma unroll
    for (int j = 0; j < 4; ++j)
      nvc[j] = *(const f32x4*)&nvphi[(size_t)n_pre[0] * 256 + c * 16 + j * 4];
#pragma unroll
    for (int rd = 0; rd < 4; ++rd) {
      f32x4 stn;
      f32x4 nvn[4];
      if (rd < 3) {
        stn = *(const f32x4*)&nvstats[n_pre[rd + 1] * 4];
#pragma unroll
        for (int j = 0; j < 4; ++j)
          nvn[j] = *(const f32x4*)&nvphi[(size_t)n_pre[rd + 1] * 256 + c * 16 + j * 4];
      }
      const int p = w * 16 + rd * 4 + q;
      const float a = a_pre[rd];
      const float mu = fmaf(a, mw, stc.x);
      const float e2 = fmaf(a * a, e2w, fmaf(a + a, stc.z, stc.y));
      const float var = fmaxf(e2 - mu * mu, 0.f);
      const float rstd = 1.f / sqrtf(var + 1e-5f);
      const float nmr = -mu * rstd;
      unsigned pk[8];
#pragma unroll
      for (int j = 0; j < 4; ++j) {
        float hh[4];
#pragma unroll
        for (int u = 0; u < 4; ++u) {
          const float v = fmaf(a, w4[j][u], nvc[j][u]);
          const float tt = fmaf(v, rstd, nmr);
          hh[u] = gelu_tanh(fmaf(tt, g1[j][u], b1[j][u]));
        }
        pk[j * 2] = cvt_pk_bf16(hh[0], hh[1]);
        pk[j * 2 + 1] = cvt_pk_bf16(hh[2], hh[3]);
      }
      *(i32x4*)&h1s[p * 264 + c * 16] = (i32x4){(int)pk[0], (int)pk[1], (int)pk[2], (int)pk[3]};
      *(i32x4*)&h1s[p * 264 + c * 16 + 8] = (i32x4){(int)pk[4], (int)pk[5], (int)pk[6], (int)pk[7]};
      if (rd < 3) {
        stc = stn;
#pragma unroll
        for (int j = 0; j < 4; ++j) nvc[j] = nvn[j];
      }
    }
  }
  // ---- Phase B ----
  const u16* Bb = pW2T + ((size_t)(w * 64 + c) << 8) + q * 8;
  short8 be[4], bo[4];
#pragma unroll
  for (int nt = 0; nt < 4; ++nt) be[nt] = *(const short8*)&Bb[nt * 4096];
#pragma unroll
  for (int nt = 0; nt < 4; ++nt) bo[nt] = *(const short8*)&Bb[nt * 4096 + 32];
  f32x4 acc[4][4];
#pragma unroll
  for (int nt = 0; nt < 4; ++nt) {
    const float bz = pb2[w * 64 + nt * 16 + c];
#pragma unroll
    for (int mt = 0; mt < 4; ++mt) acc[mt][nt] = (f32x4){bz, bz, bz, bz};
  }
  __syncthreads();  // B2
#pragma unroll
  for (int ks2 = 0; ks2 < 4; ++ks2) {
    {
      short8 av[4];
#pragma unroll
      for (int mt = 0; mt < 4; ++mt)
        av[mt] = *(const short8*)&h1s[(mt * 16 + c) * 264 + ks2 * 64 + q * 8];
#pragma unroll
      for (int mt = 0; mt < 4; ++mt)
#pragma unroll
        for (int nt = 0; nt < 4; ++nt)
          acc[mt][nt] =
              __builtin_amdgcn_mfma_f32_16x16x32_bf16(av[mt], be[nt], acc[mt][nt], 0, 0, 0);
      if (ks2 < 3) {
#pragma unroll
        for (int nt = 0; nt < 4; ++nt)
          be[nt] = *(const short8*)&Bb[nt * 4096 + ks2 * 64 + 64];
      }
    }
    {
      short8 av[4];
#pragma unroll
      for (int mt = 0; mt < 4; ++mt)
        av[mt] = *(const short8*)&h1s[(mt * 16 + c) * 264 + ks2 * 64 + 32 + q * 8];
#pragma unroll
      for (int mt = 0; mt < 4; ++mt)
#pragma unroll
        for (int nt = 0; nt < 4; ++nt)
          acc[mt][nt] =
              __builtin_amdgcn_mfma_f32_16x16x32_bf16(av[mt], bo[nt], acc[mt][nt], 0, 0, 0);
      if (ks2 < 3) {
#pragma unroll
        for (int nt = 0; nt < 4; ++nt)
          bo[nt] = *(const short8*)&Bb[nt * 4096 + ks2 * 64 + 96];
      }
    }
  }
  __syncthreads();  // B3
  // ---- Phase C: LN2 stats via LDS transpose reduce ----
  float* sbuf = (float*)h1s;
  float* s2buf = sbuf + 64 * 66;
#pragma unroll
  for (int mt = 0; mt < 4; ++mt)
#pragma unroll
    for (int reg = 0; reg < 4; ++reg) {
      const float v0 = acc[mt][0][reg], v1 = acc[mt][1][reg];
      const float v2 = acc[mt][2][reg], v3 = acc[mt][3][reg];
      const float s = (v0 + v1) + (v2 + v3);
      float s2 = v0 * v0;
      s2 = fmaf(v1, v1, s2);
      s2 = fmaf(v2, v2, s2);
      s2 = fmaf(v3, v3, s2);
      const int r = mt * 16 + q * 4 + reg;
      sbuf[r * 66 + w * 16 + c] = s;
      s2buf[r * 66 + w * 16 + c] = s2;
    }
  __syncthreads();  // B4
  {
    const int r = tid >> 2, seg = tid & 3;
    const float* rp = &sbuf[r * 66 + seg * 16];
    const float* rp2 = &s2buf[r * 66 + seg * 16];
    float ss = 0.f, ss2 = 0.f;
#pragma unroll
    for (int j = 0; j < 8; ++j) {
      const f32x2 u = *(const f32x2*)&rp[j * 2];
      const f32x2 u2 = *(const f32x2*)&rp2[j * 2];
      ss += u[0] + u[1];
      ss2 += u2[0] + u2[1];
    }
    ss += __shfl_xor(ss, 1);
    ss2 += __shfl_xor(ss2, 1);
    ss += __shfl_xor(ss, 2);
    ss2 += __shfl_xor(ss2, 2);
    if (seg == 0) {
      const float mu = ss * (1.f / 256.f);
      const float var = fmaxf(ss2 * (1.f / 256.f) - mu * mu, 0.f);
      const float rstd = 1.f / sqrtf(var + 1e-5f);
      rowstats[r * 2] = mu;
      rowstats[r * 2 + 1] = rstd;
    }
  }
  __syncthreads();  // B5
  float g2v[4], b2v[4], aggl[4];
#pragma unroll
  for (int nt = 0; nt < 4; ++nt) {
    g2v[nt] = pln2_g[w * 64 + nt * 16 + c];
    b2v[nt] = pln2_b[w * 64 + nt * 16 + c];
    aggl[nt] = 16.f * b2v[nt];
  }
#pragma unroll
  for (int mt = 0; mt < 4; ++mt)
#pragma unroll
    for (int reg = 0; reg < 4; ++reg) {
      const int r = mt * 16 + q * 4 + reg;
      const f32x2 mr = *(const f32x2*)&rowstats[r * 2];
      const float nmr = -mr[0] * mr[1];
#pragma unroll
      for (int nt = 0; nt < 4; ++nt) {
        const float tt = fmaf(acc[mt][nt][reg], mr[1], nmr);
        aggl[nt] = fmaf(tt, g2v[nt], aggl[nt]);
      }
    }
  float* aggb = sbuf;
#pragma unroll
  for (int nt = 0; nt < 4; ++nt) {
    float vs = aggl[nt];
    vs += __shfl_xor(vs, 16);
    vs += __shfl_xor(vs, 32);
    if (q == 0) aggb[w * 64 + nt * 16 + c] = vs;
  }
  __syncthreads();  // B6
  const float v = aggb[tid];
  float s = v, s2 = v * v;
  waveRed2(s, s2);
  if ((tid & 63) == 0) { red[(tid >> 6) * 2] = s; red[(tid >> 6) * 2 + 1] = s2; }
  __syncthreads();  // B7
  s = red[0] + red[2] + red[4] + red[6];
  s2 = red[1] + red[3] + red[5] + red[7];
  const float mu = s * (1.f / 256.f);
  const float var = fmaxf(s2 * (1.f / 256.f) - mu * mu, 0.f);
  const float rstd = 1.f / sqrtf(var + 1e-5f);
  rh[(size_t)t * 256 + tid] = f2bf((v - mu) * rstd * rln_g[tid] + rln_b[tid]);
}

// ---------------- launch ----------------
extern "C" void kernel_launch(void* const* d_in, const int* in_sizes, int n_in,
                              void* d_out, int out_size, void* d_ws, size_t ws_size,
                              hipStream_t stream) {
  const float* x = (const float*)d_in[0];
  const float* W_in = (const float*)d_in[1];
  const float* nv = (const float*)d_in[2];
  const float* Wr1 = (const float*)d_in[3];
  const float* Wr2 = (const float*)d_in[4];
  const float* rn_g = (const float*)d_in[5];
  const float* rn_b = (const float*)d_in[6];
  const float* pW1 = (const float*)d_in[7];
  const float* pb1 = (const float*)d_in[8];
  const float* pln1_g = (const float*)d_in[9];
  const float* pln1_b = (const float*)d_in[10];
  const float* pW2 = (const float*)d_in[11];
  const float* pb2 = (const float*)d_in[12];
  const float* pln2_g = (const float*)d_in[13];
  const float* pln2_b = (const float*)d_in[14];
  const float* rln_g = (const float*)d_in[15];
  const float* rln_b = (const float*)d_in[16];
  const float* rW1 = (const float*)d_in[17];
  const float* rb1 = (const float*)d_in[18];
  const float* rW2 = (const float*)d_in[19];
  const float* rb2 = (const float*)d_in[20];
  float* out = (float*)d_out;
  const int T = in_sizes[0] / 512;  // 4096

  float* ws = (float*)d_ws;
  float* xln = ws;    ws += (size_t)T * 512;
  float* h = ws;      ws += (size_t)T * 512;
  float* nvphi = ws;  ws += (size_t)2048 * 256;
  float* nvstats = ws; ws += (size_t)2048 * 4;
  float* actb = ws;   ws += (size_t)T * 64;
  int* idx = (int*)ws;   ws += (size_t)T * 64;
  u16* scoresb = (u16*)ws; ws += (size_t)T * 2048 / 2;
  u16* hb = (u16*)ws;    ws += (size_t)T * 512 / 2;
  u16* Wr2b = (u16*)ws;  ws += (size_t)2048 * 512 / 2;
  u16* pW2T = (u16*)ws;  ws += (size_t)2048 * 256 / 2;
  u16* rh = (u16*)ws;    ws += (size_t)T * 256 / 2;
  u16* t1b = (u16*)ws;   ws += (size_t)T * 512 / 2;
  u16* rW1T = (u16*)ws;  ws += (size_t)512 * 256 / 2;
  u16* rW2T = (u16*)ws;  ws += (size_t)512 * 512 / 2;

  k_prep<<<5632 + T, 256, 0, stream>>>(nv, pW1, pb1, nvphi, nvstats, pW2, pW2T,
                                       rW1, rW1T, rW2, rW2T, Wr2, Wr2b, x, rn_g,
                                       rn_b, xln);
  gemm8f<2, true><<<dim3(512 / 64, T / 128), 256, 0, stream>>>(
      xln, Wr1, h, hb, T, 512, 512);
  gemm_mf<0, false, 1><<<dim3(2048 / 128, T / 64), 256, 0, stream>>>(
      hb, Wr2b, nullptr, scoresb, T, 2048, 512);
  k_topk_act<<<T, 256, 0, stream>>>(scoresb, h, Wr2, x, W_in, idx, actb);
  k_phi<<<T, 256, 0, stream>>>(nvphi, nvstats, pW1, pln1_g, pln1_b, pW2T, pb2,
                               pln2_g, pln2_b, idx, actb, rln_g, rln_b, rh);
  gemm_mf<1, true, 1><<<dim3(512 / 128, T / 64), 256, 0, stream>>>(
      rh, rW1T, rb1, t1b, T, 512, 256);
  gemm_mf<0, true, 0><<<dim3(512 / 128, T / 64), 256, 0, stream>>>(
      t1b, rW2T, rb2, out, T, 512, 512);
}

// Round 5
// 384.628 us; speedup vs baseline: 1.1581x; 1.0209x over previous
//
#include <hip/hip_runtime.h>
#include <cstdint>
#include <cstddef>

typedef unsigned short u16;
typedef float f32x4 __attribute__((ext_vector_type(4)));
typedef float f32x2 __attribute__((ext_vector_type(2)));
typedef short short8 __attribute__((ext_vector_type(8)));
typedef int i32x4 __attribute__((ext_vector_type(4)));

// ---------------- helpers ----------------

__device__ __forceinline__ float geluf(float v) {  // exact (libm erff)
  return 0.5f * v * (1.0f + erff(v * 0.70710678118654752440f));
}

// Abramowitz-Stegun 7.1.26: |err| <= 1.5e-7 abs.
__device__ __forceinline__ float erf_fast(float x) {
  const float ax = fabsf(x);
  const float t = __builtin_amdgcn_rcpf(fmaf(0.3275911f, ax, 1.0f));
  float p = fmaf(1.061405429f, t, -1.453152027f);
  p = fmaf(p, t, 1.421413741f);
  p = fmaf(p, t, -0.284496736f);
  p = fmaf(p, t, 0.254829592f);
  p = p * t;
  const float e = __expf(-ax * ax);
  const float r = fmaf(-p, e, 1.0f);
  return copysignf(r, x);
}
__device__ __forceinline__ float gelu_fast(float v) {
  return 0.5f * v * (1.0f + erf_fast(v * 0.70710678118654752440f));
}

// tanh-form gelu: |err vs erf-gelu| ~3e-4 abs — below bf16 storage quantum.
__device__ __forceinline__ float gelu_tanh(float x) {
  const float x2 = x * x;
  const float u = fmaf(0.044715f, x2, 1.0f);
  const float z = x * u * 2.3022077f;
  const float e = exp2f(z);
  const float r = __builtin_amdgcn_rcpf(e + 1.0f);
  return fmaf(-x, r, x);
}

__device__ __forceinline__ u16 f2bf(float f) {  // RNE fp32 -> bf16 bits
  unsigned u = __float_as_uint(f);
  u = (u + 0x7FFFu + ((u >> 16) & 1u)) >> 16;
  return (u16)u;
}
__device__ __forceinline__ float bf2f(u16 h) {
  return __uint_as_float(((unsigned)h) << 16);
}

__device__ __forceinline__ unsigned cvt_pk_bf16(float lo, float hi) {
  unsigned r;
  asm("v_cvt_pk_bf16_f32 %0, %1, %2" : "=v"(r) : "v"(lo), "v"(hi));
  return r;
}

// async global->LDS, 16B per lane; LDS dest must be WAVE-UNIFORM base
// (HW writes lane l at base + l*16). Completion tracked by vmcnt; the
// compiler's s_waitcnt vmcnt(0) before s_barrier (inside __syncthreads)
// is the drain point.
typedef const __attribute__((address_space(1))) unsigned int ga_u32;
typedef __attribute__((address_space(3))) unsigned int la_u32;
__device__ __forceinline__ void gload_lds16(const u16* g, u16* l) {
  __builtin_amdgcn_global_load_lds((ga_u32*)g, (la_u32*)l, 16, 0, 0);
}

__device__ __forceinline__ void waveRed2(float& s, float& s2) {
#pragma unroll
  for (int m = 1; m < 64; m <<= 1) {
    s += __shfl_xor(s, m);
    s2 += __shfl_xor(s2, m);
  }
}

// ---------------- fused prep: nvphi(+stats) + converts + router-LN ----------------
__global__ __launch_bounds__(256) void k_prep(
    const float* __restrict__ nv, const float* __restrict__ pW1,
    const float* __restrict__ pb1, float* __restrict__ nvphi,
    float* __restrict__ nvstats, const float* __restrict__ pW2,
    u16* __restrict__ pW2T, const float* __restrict__ rW1,
    u16* __restrict__ rW1T, const float* __restrict__ rW2,
    u16* __restrict__ rW2T, const float* __restrict__ Wr2,
    u16* __restrict__ Wr2b, const float* __restrict__ x,
    const float* __restrict__ rn_g, const float* __restrict__ rn_b,
    float* __restrict__ xln) {
  __shared__ __align__(16) float sbuf[1536 + 96];
  const int b = blockIdx.x, tid = threadIdx.x;
  if (b < 256) {
    const int n0 = b * 8;
#pragma unroll
    for (int j = 0; j < 4; ++j) {
      const int e = tid + j * 256;  // e = k*128 + i
      sbuf[(e & 127) * 12 + (e >> 7)] = nv[n0 * 128 + e];
    }
    __syncthreads();
    float acc[8] = {};
#pragma unroll 2
    for (int i = 0; i < 128; ++i) {
      const float wv_ = pW1[i * 256 + tid];
      const f32x4 nA = *(const f32x4*)&sbuf[i * 12];
      const f32x4 nB = *(const f32x4*)&sbuf[i * 12 + 4];
      acc[0] = fmaf(nA[0], wv_, acc[0]);
      acc[1] = fmaf(nA[1], wv_, acc[1]);
      acc[2] = fmaf(nA[2], wv_, acc[2]);
      acc[3] = fmaf(nA[3], wv_, acc[3]);
      acc[4] = fmaf(nB[0], wv_, acc[4]);
      acc[5] = fmaf(nB[1], wv_, acc[5]);
      acc[6] = fmaf(nB[2], wv_, acc[6]);
      acc[7] = fmaf(nB[3], wv_, acc[7]);
    }
    const float pb = pb1[tid];
    const float wact = pW1[128 * 256 + tid];
    float* redN = sbuf + 1536;
#pragma unroll
    for (int kk = 0; kk < 8; ++kk) {
      const float s = acc[kk] + pb;
      nvphi[(size_t)(n0 + kk) * 256 + tid] = s;
      float a1 = s, a2 = s * s, a3 = s * wact;
#pragma unroll
      for (int m = 1; m < 64; m <<= 1) {
        a1 += __shfl_xor(a1, m);
        a2 += __shfl_xor(a2, m);
        a3 += __shfl_xor(a3, m);
      }
      if ((tid & 63) == 0) {
        const int w4 = tid >> 6;
        redN[w4 * 24 + kk * 3 + 0] = a1;
        redN[w4 * 24 + kk * 3 + 1] = a2;
        redN[w4 * 24 + kk * 3 + 2] = a3;
      }
    }
    __syncthreads();
    if (tid < 24) {
      const int kk = tid / 3, st = tid - kk * 3;
      const float v = redN[tid] + redN[24 + tid] + redN[48 + tid] + redN[72 + tid];
      nvstats[(size_t)(n0 + kk) * 4 + st] = v * (1.f / 256.f);
    } else if (tid < 32) {
      nvstats[(size_t)(n0 + tid - 24) * 4 + 3] = 0.f;
    }
  } else if (b < 512) {
    const int n = b - 256;
    pW2T[n * 256 + tid] = f2bf(pW2[tid * 256 + n]);
  } else if (b < 1024) {
    const int n = b - 512;
    rW1T[(size_t)n * 256 + tid] = f2bf(rW1[(size_t)tid * 512 + n]);
  } else if (b < 1536) {
    const int n = b - 1024;
    for (int k = tid; k < 512; k += 256)
      rW2T[(size_t)n * 512 + k] = f2bf(rW2[(size_t)k * 512 + n]);
  } else if (b < 5632) {
    const int i = (b - 1536) * 256 + tid;
    Wr2b[i] = f2bf(Wr2[i]);
  } else {
    float* red = sbuf;
    const int t = b - 5632;
    const float v0 = x[(size_t)t * 512 + tid];
    const float v1 = x[(size_t)t * 512 + 256 + tid];
    float s = v0 + v1, s2 = v0 * v0 + v1 * v1;
    waveRed2(s, s2);
    if ((tid & 63) == 0) { red[(tid >> 6) * 2] = s; red[(tid >> 6) * 2 + 1] = s2; }
    __syncthreads();
    s = red[0] + red[2] + red[4] + red[6];
    s2 = red[1] + red[3] + red[5] + red[7];
    const float mu = s * (1.f / 512.f);
    const float var = fmaxf(s2 * (1.f / 512.f) - mu * mu, 0.f);
    const float rstd = 1.f / sqrtf(var + 1e-5f);
    xln[(size_t)t * 512 + tid] = (v0 - mu) * rstd * rn_g[tid] + rn_b[tid];
    xln[(size_t)t * 512 + 256 + tid] =
        (v1 - mu) * rstd * rn_g[tid + 256] + rn_b[tid + 256];
  }
}

// ---------------- 128x64 fp32 GEMM, C = act(A[M,K] @ B[N,K]^T) ----------------
// R18: single-barrier double-buffered LDS (32 barriers instead of 64).
// Per-output k-summation order unchanged -> h identical (selection-critical).
template <int GMODE, bool BF16OUT>
__global__ __launch_bounds__(256) void gemm8f(const float* __restrict__ A,
                                              const float* __restrict__ B,
                                              float* __restrict__ C,
                                              u16* __restrict__ Cb, int M,
                                              int N, int K) {
  __shared__ float As[2][16][132];
  __shared__ float Bs[2][16][68];
  const int tid = threadIdx.x;
  const int tm = tid >> 4, tn = tid & 15;
  const int m0 = blockIdx.y * 128, n0 = blockIdx.x * 64;
  const int sr = tid >> 1, sk = (tid & 1) * 8;    // A stage: 128 rows x 8 k
  const int srB = tid >> 2, skB = (tid & 3) * 4;  // B stage: 64 rows x 4 k
  const float* gA = &A[(size_t)(m0 + sr) * K + sk];
  const float* gB = &B[(size_t)(n0 + srB) * K + skB];
  float acc[8][4] = {};
  float4 a0 = *(const float4*)&gA[0];
  float4 a1 = *(const float4*)&gA[4];
  float4 b0 = *(const float4*)&gB[0];
  const int nk0 = K >> 4;
  int buf = 0;
  for (int it = 0; it < nk0; ++it) {
    As[buf][sk + 0][sr] = a0.x; As[buf][sk + 1][sr] = a0.y; As[buf][sk + 2][sr] = a0.z; As[buf][sk + 3][sr] = a0.w;
    As[buf][sk + 4][sr] = a1.x; As[buf][sk + 5][sr] = a1.y; As[buf][sk + 6][sr] = a1.z; As[buf][sk + 7][sr] = a1.w;
    Bs[buf][skB + 0][srB] = b0.x; Bs[buf][skB + 1][srB] = b0.y; Bs[buf][skB + 2][srB] = b0.z; Bs[buf][skB + 3][srB] = b0.w;
    __syncthreads();
    if (it + 1 < nk0) {
      const int k0 = (it + 1) * 16;
      a0 = *(const float4*)&gA[k0];
      a1 = *(const float4*)&gA[k0 + 4];
      b0 = *(const float4*)&gB[k0];
    }
#pragma unroll
    for (int k = 0; k < 16; ++k) {
      float a[8], bb[4];
      *(float4*)&a[0] = *(const float4*)&As[buf][k][tm * 8];
      *(float4*)&a[4] = *(const float4*)&As[buf][k][tm * 8 + 4];
      *(float4*)&bb[0] = *(const float4*)&Bs[buf][k][tn * 4];
#pragma unroll
      for (int i = 0; i < 8; ++i)
#pragma unroll
        for (int j = 0; j < 4; ++j) acc[i][j] = fmaf(a[i], bb[j], acc[i][j]);
    }
    buf ^= 1;
  }
#pragma unroll
  for (int i = 0; i < 8; ++i) {
    float4 o0;
    float* p0 = (float*)&o0;
#pragma unroll
    for (int j = 0; j < 4; ++j) {
      float xv = acc[i][j];
      if (GMODE == 1) xv = gelu_fast(xv);
      if (GMODE == 2) xv = geluf(xv);
      p0[j] = xv;
    }
    const size_t off = (size_t)(m0 + tm * 8 + i) * N + n0 + tn * 4;
    *(float4*)&C[off] = o0;
    if (BF16OUT) {
      ushort4 u0;
      u0.x = f2bf(p0[0]); u0.y = f2bf(p0[1]); u0.z = f2bf(p0[2]); u0.w = f2bf(p0[3]);
      *(ushort4*)&Cb[off] = u0;
    }
  }
}

// ---------------- MFMA GEMM: C = act(A[M,K] @ B[N,K]^T + bias) ----------------
// R18: 2-phase schedule — global_load_lds(16B) staging into double-buffered
// LINEAR LDS [row][32]; ONE barrier per 32-K step (was 2); stage of buf^1
// issues BEFORE the MFMA cluster and drains at the barrier (T3 minimum
// 2-phase recipe). NT=64 variant for the rho GEMMs doubles block count.
template <int GMODE, bool BIAS, int OUT, int NT>
__global__ __launch_bounds__(256) void gemm_mf(const u16* __restrict__ A,
                                               const u16* __restrict__ B,
                                               const float* __restrict__ bias,
                                               void* __restrict__ Cp, int M,
                                               int N, int K) {
  constexpr int ASZ = 64 * 32;        // u16
  constexpr int BSZ = NT * 32;        // u16
  constexpr int BUFSZ = ASZ + BSZ;
  __shared__ __align__(16) u16 smem[2 * BUFSZ];

  const int tid = threadIdx.x;
  const int w = tid >> 6, lane = tid & 63;
  const int q = lane >> 4, c = lane & 15;
  const int m0 = blockIdx.y * 64, n0 = blockIdx.x * NT;
  // staging: lane l covers row chunkbase + l/4, k-col (l%4)*8 (16B)
  const int lr = lane >> 2, lc = (lane & 3) * 8;
  const u16* gAs = A + (size_t)(m0 + w * 16 + lr) * K + lc;
  const u16* gBs = B + (size_t)(n0 + w * 16 + lr) * K + lc;
  const u16* gBs2 = B + (size_t)(n0 + (NT == 128 ? 64 : 0) + w * 16 + lr) * K + lc;

  f32x4 acc[NT / 16];
#pragma unroll
  for (int ct = 0; ct < NT / 16; ++ct) {
    const float bv = BIAS ? bias[n0 + ct * 16 + c] : 0.f;
    acc[ct] = (f32x4){bv, bv, bv, bv};
  }

  auto stage = [&](int b, int k0) {
    gload_lds16(gAs + k0, &smem[b * BUFSZ + w * 512]);
    gload_lds16(gBs + k0, &smem[b * BUFSZ + ASZ + w * 512]);
    if (NT == 128) gload_lds16(gBs2 + k0, &smem[b * BUFSZ + ASZ + (4 + w) * 512]);
  };

  stage(0, 0);
  __syncthreads();  // drains vmcnt -> buf0 ready
  int buf = 0;
  const int nk = K >> 5;
  for (int it = 0; it < nk; ++it) {
    if (it + 1 < nk) stage(buf ^ 1, (it + 1) * 32);  // async, in flight over MFMA
    const short8 ah = *(const short8*)&smem[buf * BUFSZ + (w * 16 + c) * 32 + q * 8];
#pragma unroll
    for (int ct = 0; ct < NT / 16; ++ct) {
      const short8 bh =
          *(const short8*)&smem[buf * BUFSZ + ASZ + (ct * 16 + c) * 32 + q * 8];
      acc[ct] = __builtin_amdgcn_mfma_f32_16x16x32_bf16(ah, bh, acc[ct], 0, 0, 0);
    }
    __syncthreads();  // drains vmcnt -> buf^1 ready; readers of buf done
    buf ^= 1;
  }
#pragma unroll
  for (int ct = 0; ct < NT / 16; ++ct) {
#pragma unroll
    for (int reg = 0; reg < 4; ++reg) {
      float v = acc[ct][reg];
      if (GMODE == 1) v = gelu_fast(v);
      const size_t off = (size_t)(m0 + w * 16 + q * 4 + reg) * N + n0 + ct * 16 + c;
      if (OUT == 0) ((float*)Cp)[off] = v;
      else          ((u16*)Cp)[off] = f2bf(v);
    }
  }
}

// ---------------- fused: top-64 (approx+exact rescore) THEN act ----------------
__global__ __launch_bounds__(256) void k_topk_act(
    const u16* __restrict__ scoresb, const float* __restrict__ h,
    const float* __restrict__ Wr2, const float* __restrict__ x,
    const float* __restrict__ W_in, int* __restrict__ idxout,
    float* __restrict__ act) {
  __shared__ float hs[512];
  __shared__ int redc[2][4];
  __shared__ int cand[160];
  __shared__ float cex[160];
  __shared__ int selidx[64];
  __shared__ unsigned ccnt;
  const int t = blockIdx.x, tid = threadIdx.x;
  hs[tid] = h[(size_t)t * 512 + tid];
  hs[tid + 256] = h[(size_t)t * 512 + 256 + tid];
  unsigned key[8];
#pragma unroll
  for (int j = 0; j < 8; ++j) {
    const unsigned u = (unsigned)scoresb[(size_t)t * 2048 + tid + 256 * j];
    key[j] = (u & 0x8000u) ? (0xFFFFu & ~u) : (u | 0x8000u);
  }
  if (tid == 0) ccnt = 0u;
  unsigned lo = 0u, hi = 0xFFFFu;
  int pb = 0;
  while (lo < hi) {
    const unsigned mid = (lo + hi + 1u) >> 1;
    int c = 0;
#pragma unroll
    for (int j = 0; j < 8; ++j) c += (key[j] >= mid);
#pragma unroll
    for (int m = 1; m < 64; m <<= 1) c += __shfl_xor(c, m);
    if ((tid & 63) == 0) redc[pb][tid >> 6] = c;
    __syncthreads();
    const int total = redc[pb][0] + redc[pb][1] + redc[pb][2] + redc[pb][3];
    if (total >= 96) lo = mid; else hi = mid - 1;
    pb ^= 1;
  }
#pragma unroll
  for (int j = 0; j < 8; ++j) {
    if (key[j] >= lo) {
      const unsigned pos = atomicAdd(&ccnt, 1u);
      if (pos < 160u) cand[pos] = tid + 256 * j;
    }
  }
  __syncthreads();
  const int cnt = (int)(ccnt < 160u ? ccnt : 160u);
  const int wv = tid >> 6, l = tid & 63;
#pragma unroll 2
  for (int ci = wv; ci < cnt; ci += 4) {
    const float* Wr = Wr2 + (size_t)cand[ci] * 512;
    float s = 0.f;
#pragma unroll
    for (int j = 0; j < 8; ++j) s = fmaf(Wr[l + 64 * j], hs[l + 64 * j], s);
#pragma unroll
    for (int m = 1; m < 64; m <<= 1) s += __shfl_xor(s, m);
    if (l == 0) cex[ci] = s;
  }
  __syncthreads();
  if (tid < cnt) {
    const float my = cex[tid];
    const int myi = cand[tid];
    int rank = 0;
    for (int j = 0; j < cnt; ++j) {
      const float oj = cex[j];
      const int oi = cand[j];
      rank += (oj > my) || (oj == my && oi < myi);
    }
    if (rank < 64) {
      selidx[rank] = myi;
      idxout[(size_t)t * 64 + rank] = myi;
    }
  }
  __syncthreads();
  hs[tid] = x[(size_t)t * 512 + tid];
  hs[tid + 256] = x[(size_t)t * 512 + 256 + tid];
  __syncthreads();
  const float4 xa = *(const float4*)&hs[l * 8];
  const float4 xb = *(const float4*)&hs[l * 8 + 4];
#pragma unroll 2
  for (int qq = 0; qq < 16; ++qq) {
    const int k = wv * 16 + qq;
    const int n = selidx[k];
    const float* Wr = W_in + (size_t)n * 512 + l * 8;
    const float4 wa = *(const float4*)Wr;
    const float4 wb = *(const float4*)(Wr + 4);
    float s = wa.x * xa.x;
    s = fmaf(wa.y, xa.y, s); s = fmaf(wa.z, xa.z, s); s = fmaf(wa.w, xa.w, s);
    s = fmaf(wb.x, xb.x, s); s = fmaf(wb.y, xb.y, s);
    s = fmaf(wb.z, xb.z, s); s = fmaf(wb.w, xb.w, s);
#pragma unroll
    for (int m = 1; m < 64; m <<= 1) s += __shfl_xor(s, m);
    if (l == 0) act[(size_t)t * 64 + k] = gelu_fast(s);
  }
}

// ---------------- fused phi + rho-LN (one token per block) ----------------
// R16 (locked): analytic LN1 stats; tanh-gelu; per-wave idx/act loads;
// Phase-A rd+1 prefetch; Phase-B double-buffered b-fragment prefetch.
__global__ __launch_bounds__(256, 4) void k_phi(
    const float* __restrict__ nvphi, const float* __restrict__ nvstats,
    const float* __restrict__ pW1, const float* __restrict__ pln1_g,
    const float* __restrict__ pln1_b, const u16* __restrict__ pW2T,
    const float* __restrict__ pb2, const float* __restrict__ pln2_g,
    const float* __restrict__ pln2_b, const int* __restrict__ idx,
    const float* __restrict__ act, const float* __restrict__ rln_g,
    const float* __restrict__ rln_b, u16* __restrict__ rh) {
  __shared__ __align__(16) u16 h1s[64 * 264];
  __shared__ float rowstats[64 * 2];
  __shared__ float red[8];
  const int tid = threadIdx.x;
  const int t = blockIdx.x;
  const int w = tid >> 6, lane = tid & 63;
  const int q = lane >> 4, c = lane & 15;
  {
    int n_pre[4];
    float a_pre[4];
#pragma unroll
    for (int rd = 0; rd < 4; ++rd) {
      n_pre[rd] = idx[(size_t)t * 64 + w * 16 + rd * 4 + q];
      a_pre[rd] = act[(size_t)t * 64 + w * 16 + rd * 4 + q];
    }
    f32x4 w4[4], g1[4], b1[4];
#pragma unroll
    for (int j = 0; j < 4; ++j) {
      w4[j] = *(const f32x4*)&pW1[128 * 256 + c * 16 + j * 4];
      g1[j] = *(const f32x4*)&pln1_g[c * 16 + j * 4];
      b1[j] = *(const f32x4*)&pln1_b[c * 16 + j * 4];
    }
    float sw = 0.f, sw2 = 0.f;
#pragma unroll
    for (int j = 0; j < 4; ++j)
#pragma unroll
      for (int u = 0; u < 4; ++u) {
        sw += w4[j][u];
        sw2 = fmaf(w4[j][u], w4[j][u], sw2);
      }
#pragma unroll
    for (int m = 1; m < 16; m <<= 1) {
      sw += __shfl_xor(sw, m);
      sw2 += __shfl_xor(sw2, m);
    }
    const float mw = sw * (1.f / 256.f), e2w = sw2 * (1.f / 256.f);
    f32x4 stc = *(const f32x4*)&nvstats[n_pre[0] * 4];
    f32x4 nvc[4];
#pragma unroll
    for (int j = 0; j < 4; ++j)
      nvc[j] = *(const f32x4*)&nvphi[(size_t)n_pre[0] * 256 + c * 16 + j * 4];
#pragma unroll
    for (int rd = 0; rd < 4; ++rd) {
      f32x4 stn;
      f32x4 nvn[4];
      if (rd < 3) {
        stn = *(const f32x4*)&nvstats[n_pre[rd + 1] * 4];
#pragma unroll
        for (int j = 0; j < 4; ++j)
          nvn[j] = *(const f32x4*)&nvphi[(size_t)n_pre[rd + 1] * 256 + c * 16 + j * 4];
      }
      const int p = w * 16 + rd * 4 + q;
      const float a = a_pre[rd];
      const float mu = fmaf(a, mw, stc.x);
      const float e2 = fmaf(a * a, e2w, fmaf(a + a, stc.z, stc.y));
      const float var = fmaxf(e2 - mu * mu, 0.f);
      const float rstd = 1.f / sqrtf(var + 1e-5f);
      const float nmr = -mu * rstd;
      unsigned pk[8];
#pragma unroll
      for (int j = 0; j < 4; ++j) {
        float hh[4];
#pragma unroll
        for (int u = 0; u < 4; ++u) {
          const float v = fmaf(a, w4[j][u], nvc[j][u]);
          const float tt = fmaf(v, rstd, nmr);
          hh[u] = gelu_tanh(fmaf(tt, g1[j][u], b1[j][u]));
        }
        pk[j * 2] = cvt_pk_bf16(hh[0], hh[1]);
        pk[j * 2 + 1] = cvt_pk_bf16(hh[2], hh[3]);
      }
      *(i32x4*)&h1s[p * 264 + c * 16] = (i32x4){(int)pk[0], (int)pk[1], (int)pk[2], (int)pk[3]};
      *(i32x4*)&h1s[p * 264 + c * 16 + 8] = (i32x4){(int)pk[4], (int)pk[5], (int)pk[6], (int)pk[7]};
      if (rd < 3) {
        stc = stn;
#pragma unroll
        for (int j = 0; j < 4; ++j) nvc[j] = nvn[j];
      }
    }
  }
  const u16* Bb = pW2T + ((size_t)(w * 64 + c) << 8) + q * 8;
  short8 be[4], bo[4];
#pragma unroll
  for (int nt = 0; nt < 4; ++nt) be[nt] = *(const short8*)&Bb[nt * 4096];
#pragma unroll
  for (int nt = 0; nt < 4; ++nt) bo[nt] = *(const short8*)&Bb[nt * 4096 + 32];
  f32x4 acc[4][4];
#pragma unroll
  for (int nt = 0; nt < 4; ++nt) {
    const float bz = pb2[w * 64 + nt * 16 + c];
#pragma unroll
    for (int mt = 0; mt < 4; ++mt) acc[mt][nt] = (f32x4){bz, bz, bz, bz};
  }
  __syncthreads();  // B2
#pragma unroll
  for (int ks2 = 0; ks2 < 4; ++ks2) {
    {
      short8 av[4];
#pragma unroll
      for (int mt = 0; mt < 4; ++mt)
        av[mt] = *(const short8*)&h1s[(mt * 16 + c) * 264 + ks2 * 64 + q * 8];
#pragma unroll
      for (int mt = 0; mt < 4; ++mt)
#pragma unroll
        for (int nt = 0; nt < 4; ++nt)
          acc[mt][nt] =
              __builtin_amdgcn_mfma_f32_16x16x32_bf16(av[mt], be[nt], acc[mt][nt], 0, 0, 0);
      if (ks2 < 3) {
#pragma unroll
        for (int nt = 0; nt < 4; ++nt)
          be[nt] = *(const short8*)&Bb[nt * 4096 + ks2 * 64 + 64];
      }
    }
    {
      short8 av[4];
#pragma unroll
      for (int mt = 0; mt < 4; ++mt)
        av[mt] = *(const short8*)&h1s[(mt * 16 + c) * 264 + ks2 * 64 + 32 + q * 8];
#pragma unroll
      for (int mt = 0; mt < 4; ++mt)
#pragma unroll
        for (int nt = 0; nt < 4; ++nt)
          acc[mt][nt] =
              __builtin_amdgcn_mfma_f32_16x16x32_bf16(av[mt], bo[nt], acc[mt][nt], 0, 0, 0);
      if (ks2 < 3) {
#pragma unroll
        for (int nt = 0; nt < 4; ++nt)
          bo[nt] = *(const short8*)&Bb[nt * 4096 + ks2 * 64 + 96];
      }
    }
  }
  __syncthreads();  // B3
  float* sbuf = (float*)h1s;
  float* s2buf = sbuf + 64 * 66;
#pragma unroll
  for (int mt = 0; mt < 4; ++mt)
#pragma unroll
    for (int reg = 0; reg < 4; ++reg) {
      const float v0 = acc[mt][0][reg], v1 = acc[mt][1][reg];
      const float v2 = acc[mt][2][reg], v3 = acc[mt][3][reg];
      const float s = (v0 + v1) + (v2 + v3);
      float s2 = v0 * v0;
      s2 = fmaf(v1, v1, s2);
      s2 = fmaf(v2, v2, s2);
      s2 = fmaf(v3, v3, s2);
      const int r = mt * 16 + q * 4 + reg;
      sbuf[r * 66 + w * 16 + c] = s;
      s2buf[r * 66 + w * 16 + c] = s2;
    }
  __syncthreads();  // B4
  {
    const int r = tid >> 2, seg = tid & 3;
    const float* rp = &sbuf[r * 66 + seg * 16];
    const float* rp2 = &s2buf[r * 66 + seg * 16];
    float ss = 0.f, ss2 = 0.f;
#pragma unroll
    for (int j = 0; j < 8; ++j) {
      const f32x2 u = *(const f32x2*)&rp[j * 2];
      const f32x2 u2 = *(const f32x2*)&rp2[j * 2];
      ss += u[0] + u[1];
      ss2 += u2[0] + u2[1];
    }
    ss += __shfl_xor(ss, 1);
    ss2 += __shfl_xor(ss2, 1);
    ss += __shfl_xor(ss, 2);
    ss2 += __shfl_xor(ss2, 2);
    if (seg == 0) {
      const float mu = ss * (1.f / 256.f);
      const float var = fmaxf(ss2 * (1.f / 256.f) - mu * mu, 0.f);
      const float rstd = 1.f / sqrtf(var + 1e-5f);
      rowstats[r * 2] = mu;
      rowstats[r * 2 + 1] = rstd;
    }
  }
  __syncthreads();  // B5
  float g2v[4], b2v[4], aggl[4];
#pragma unroll
  for (int nt = 0; nt < 4; ++nt) {
    g2v[nt] = pln2_g[w * 64 + nt * 16 + c];
    b2v[nt] = pln2_b[w * 64 + nt * 16 + c];
    aggl[nt] = 16.f * b2v[nt];
  }
#pragma unroll
  for (int mt = 0; mt < 4; ++mt)
#pragma unroll
    for (int reg = 0; reg < 4; ++reg) {
      const int r = mt * 16 + q * 4 + reg;
      const f32x2 mr = *(const f32x2*)&rowstats[r * 2];
      const float nmr = -mr[0] * mr[1];
#pragma unroll
      for (int nt = 0; nt < 4; ++nt) {
        const float tt = fmaf(acc[mt][nt][reg], mr[1], nmr);
        aggl[nt] = fmaf(tt, g2v[nt], aggl[nt]);
      }
    }
  float* aggb = sbuf;
#pragma unroll
  for (int nt = 0; nt < 4; ++nt) {
    float vs = aggl[nt];
    vs += __shfl_xor(vs, 16);
    vs += __shfl_xor(vs, 32);
    if (q == 0) aggb[w * 64 + nt * 16 + c] = vs;
  }
  __syncthreads();  // B6
  const float v = aggb[tid];
  float s = v, s2 = v * v;
  waveRed2(s, s2);
  if ((tid & 63) == 0) { red[(tid >> 6) * 2] = s; red[(tid >> 6) * 2 + 1] = s2; }
  __syncthreads();  // B7
  s = red[0] + red[2] + red[4] + red[6];
  s2 = red[1] + red[3] + red[5] + red[7];
  const float mu = s * (1.f / 256.f);
  const float var = fmaxf(s2 * (1.f / 256.f) - mu * mu, 0.f);
  const float rstd = 1.f / sqrtf(var + 1e-5f);
  rh[(size_t)t * 256 + tid] = f2bf((v - mu) * rstd * rln_g[tid] + rln_b[tid]);
}

// ---------------- launch ----------------
extern "C" void kernel_launch(void* const* d_in, const int* in_sizes, int n_in,
                              void* d_out, int out_size, void* d_ws, size_t ws_size,
                              hipStream_t stream) {
  const float* x = (const float*)d_in[0];
  const float* W_in = (const float*)d_in[1];
  const float* nv = (const float*)d_in[2];
  const float* Wr1 = (const float*)d_in[3];
  const float* Wr2 = (const float*)d_in[4];
  const float* rn_g = (const float*)d_in[5];
  const float* rn_b = (const float*)d_in[6];
  const float* pW1 = (const float*)d_in[7];
  const float* pb1 = (const float*)d_in[8];
  const float* pln1_g = (const float*)d_in[9];
  const float* pln1_b = (const float*)d_in[10];
  const float* pW2 = (const float*)d_in[11];
  const float* pb2 = (const float*)d_in[12];
  const float* pln2_g = (const float*)d_in[13];
  const float* pln2_b = (const float*)d_in[14];
  const float* rln_g = (const float*)d_in[15];
  const float* rln_b = (const float*)d_in[16];
  const float* rW1 = (const float*)d_in[17];
  const float* rb1 = (const float*)d_in[18];
  const float* rW2 = (const float*)d_in[19];
  const float* rb2 = (const float*)d_in[20];
  float* out = (float*)d_out;
  const int T = in_sizes[0] / 512;  // 4096

  float* ws = (float*)d_ws;
  float* xln = ws;    ws += (size_t)T * 512;
  float* h = ws;      ws += (size_t)T * 512;
  float* nvphi = ws;  ws += (size_t)2048 * 256;
  float* nvstats = ws; ws += (size_t)2048 * 4;
  float* actb = ws;   ws += (size_t)T * 64;
  int* idx = (int*)ws;   ws += (size_t)T * 64;
  u16* scoresb = (u16*)ws; ws += (size_t)T * 2048 / 2;
  u16* hb = (u16*)ws;    ws += (size_t)T * 512 / 2;
  u16* Wr2b = (u16*)ws;  ws += (size_t)2048 * 512 / 2;
  u16* pW2T = (u16*)ws;  ws += (size_t)2048 * 256 / 2;
  u16* rh = (u16*)ws;    ws += (size_t)T * 256 / 2;
  u16* t1b = (u16*)ws;   ws += (size_t)T * 512 / 2;
  u16* rW1T = (u16*)ws;  ws += (size_t)512 * 256 / 2;
  u16* rW2T = (u16*)ws;  ws += (size_t)512 * 512 / 2;

  k_prep<<<5632 + T, 256, 0, stream>>>(nv, pW1, pb1, nvphi, nvstats, pW2, pW2T,
                                       rW1, rW1T, rW2, rW2T, Wr2, Wr2b, x, rn_g,
                                       rn_b, xln);
  gemm8f<2, true><<<dim3(512 / 64, T / 128), 256, 0, stream>>>(
      xln, Wr1, h, hb, T, 512, 512);
  gemm_mf<0, false, 1, 128><<<dim3(2048 / 128, T / 64), 256, 0, stream>>>(
      hb, Wr2b, nullptr, scoresb, T, 2048, 512);
  k_topk_act<<<T, 256, 0, stream>>>(scoresb, h, Wr2, x, W_in, idx, actb);
  k_phi<<<T, 256, 0, stream>>>(nvphi, nvstats, pW1, pln1_g, pln1_b, pW2T, pb2,
                               pln2_g, pln2_b, idx, actb, rln_g, rln_b, rh);
  gemm_mf<1, true, 1, 64><<<dim3(512 / 64, T / 64), 256, 0, stream>>>(
      rh, rW1T, rb1, t1b, T, 512, 256);
  gemm_mf<0, true, 0, 64><<<dim3(512 / 64, T / 64), 256, 0, stream>>>(
      t1b, rW2T, rb2, out, T, 512, 512);
}